// Round 9
// baseline (669.849 us; speedup 1.0000x reference)
//
#include <hip/hip_runtime.h>
#include <cstdint>
#include <cstddef>

#define B_  2
#define S_  2048
#define D_  4096
#define QH_ 32
#define NH_ 8
#define HD_ 128
#define MROWS (B_ * S_)                      // 4096
#define NQKV  (QH_ * HD_ + 2 * NH_ * HD_)    // 6144
#define KOFF  (QH_ * HD_)                    // 4096
#define VOFF  (QH_ * HD_ + NH_ * HD_)        // 5120

typedef __attribute__((ext_vector_type(8))) short bf16x8;
typedef __attribute__((ext_vector_type(4))) float f32x4;

__device__ __forceinline__ unsigned short f2bf(float f) {
    unsigned int u = __float_as_uint(f);
    return (unsigned short)((u + 0x7FFFu + ((u >> 16) & 1u)) >> 16);
}
__device__ __forceinline__ float bf2f(unsigned short h) { return __uint_as_float(((unsigned int)h) << 16); }

__device__ __forceinline__ void gl2lds16(const void* g, void* l) {
    __builtin_amdgcn_global_load_lds(
        (const __attribute__((address_space(1))) void*)g,
        (__attribute__((address_space(3))) void*)l, 16, 0, 0);
}

// ---------------------------------------------------------------------------
// fp32 -> bf16 straight convert (x). 8 elems/thread.
// ---------------------------------------------------------------------------
__global__ __launch_bounds__(256)
void convert_bf16_kernel(const float* __restrict__ in, unsigned short* __restrict__ out)
{
    const size_t i = ((size_t)blockIdx.x * 256 + threadIdx.x) * 8;
    float4 a = *(const float4*)(in + i);
    float4 b = *(const float4*)(in + i + 4);
    uint4 o;
    o.x = (unsigned int)f2bf(a.x) | ((unsigned int)f2bf(a.y) << 16);
    o.y = (unsigned int)f2bf(a.z) | ((unsigned int)f2bf(a.w) << 16);
    o.z = (unsigned int)f2bf(b.x) | ((unsigned int)f2bf(b.y) << 16);
    o.w = (unsigned int)f2bf(b.z) | ((unsigned int)f2bf(b.w) << 16);
    *(uint4*)(out + i) = o;
}

// ---------------------------------------------------------------------------
// Tile transpose-convert: in fp32 [R][C] (slab z) -> out bf16 [C][R]
// ---------------------------------------------------------------------------
__global__ __launch_bounds__(256)
void transpose_conv_kernel(const float* __restrict__ in, unsigned short* __restrict__ out,
                           int R, int C)
{
    __shared__ unsigned short tile[64][72];
    const int t  = threadIdx.x;
    const int c0 = blockIdx.x * 64;
    const int r0 = blockIdx.y * 64;
    in  += (size_t)blockIdx.z * R * C;
    out += (size_t)blockIdx.z * R * C;
    {
        const int rr = t >> 4;
        const int cc = (t & 15) * 4;
        #pragma unroll
        for (int p = 0; p < 4; ++p) {
            float4 v = *(const float4*)(in + (size_t)(r0 + p * 16 + rr) * C + c0 + cc);
            unsigned int lo = (unsigned int)f2bf(v.x) | ((unsigned int)f2bf(v.y) << 16);
            unsigned int hi = (unsigned int)f2bf(v.z) | ((unsigned int)f2bf(v.w) << 16);
            *(uint2*)&tile[p * 16 + rr][cc] = make_uint2(lo, hi);
        }
    }
    __syncthreads();
    {
        const int j  = t >> 3;
        const int i8 = (t & 7) * 8;
        #pragma unroll
        for (int p = 0; p < 2; ++p) {
            unsigned short tmp[8];
            #pragma unroll
            for (int e = 0; e < 8; ++e) tmp[e] = tile[i8 + e][p * 32 + j];
            *(uint4*)(out + (size_t)(c0 + p * 32 + j) * R + r0 + i8) = *(uint4*)tmp;
        }
    }
}

// ---------------------------------------------------------------------------
// bf16 transpose of the V slab of qkv: -> vt[(b*8+kh)*128 + h][2048 s]
// ---------------------------------------------------------------------------
__global__ __launch_bounds__(256)
void transpose_v_kernel(const unsigned short* __restrict__ qkv, unsigned short* __restrict__ vt)
{
    __shared__ unsigned short tile[64][76];
    const int t  = threadIdx.x;
    const int z  = blockIdx.z;            // b*8+kh
    const int b  = z >> 3, kh = z & 7;
    const int h0 = blockIdx.x * 64;
    const int s0 = blockIdx.y * 64;
    const unsigned short* in = qkv + (size_t)(b * S_) * NQKV + VOFF + kh * HD_;
    unsigned short* outb = vt + (size_t)z * HD_ * S_;
    {
        const int rr = t >> 4;            // s-local
        const int cc = (t & 15) * 4;      // h-local
        #pragma unroll
        for (int p = 0; p < 4; ++p) {
            uint2 v = *(const uint2*)(in + (size_t)(s0 + p * 16 + rr) * NQKV + h0 + cc);
            *(uint2*)&tile[p * 16 + rr][cc] = v;
        }
    }
    __syncthreads();
    {
        const int j  = t >> 3;            // h-local 0..31
        const int i8 = (t & 7) * 8;       // s-local
        #pragma unroll
        for (int p = 0; p < 2; ++p) {
            unsigned short tmp[8];
            #pragma unroll
            for (int e = 0; e < 8; ++e) tmp[e] = tile[i8 + e][p * 32 + j];
            *(uint4*)(outb + (size_t)(h0 + p * 32 + j) * S_ + s0 + i8) = *(uint4*)tmp;
        }
    }
}

// ---------------------------------------------------------------------------
// 128x256 GEMM, BK=32, triple-buffered (72 KiB -> 2 blocks/CU co-resident),
// 4 waves (1M x 4N), per-wave output 128x64. ONE barrier + ONE counted
// vmcnt(6) gate per K-tile (never 0 in-loop); tile kt+2 staged inside tile
// kt (2-tile prefetch lead). Co-resident block overlaps this block's
// barrier/read phase with its MFMA burst (m114/m97 mechanism). Grids divide
// the machine exactly: QKV 768 = 3 rounds, Oproj 512 = 2 rounds (no tail).
// Write-after-read proof unchanged from round 6/8: buffer (kt+2)%3 was last
// read in tile kt-1, finished by all waves before tile kt's boundary barrier.
// ---------------------------------------------------------------------------
template<int CF32>
__global__ __launch_bounds__(256, 2)
void gemm128_kernel(const unsigned short* __restrict__ A,
                    const unsigned short* __restrict__ Bt,
                    void* __restrict__ Cp, int Nst, int K)
{
    __shared__ alignas(16) unsigned short ldsA[3][128][32];  // 24 KiB
    __shared__ alignas(16) unsigned short ldsB[3][256][32];  // 48 KiB

    const int t = threadIdx.x, l = t & 63, w = t >> 6;       // 4 waves
    const int gx  = gridDim.x;
    const int nwg = gx * gridDim.y;
    int lin = blockIdx.y * gx + blockIdx.x;
    lin = (lin & 7) * (nwg >> 3) + (lin >> 3);               // bijective XCD swizzle (nwg%8==0)
    const int bn = (lin % gx) * 256, bm = (lin / gx) * 128;
    const int lm = l & 15, lg = l >> 4;

    f32x4 acc[8][4];
    #pragma unroll
    for (int i = 0; i < 8; ++i)
        #pragma unroll
        for (int j = 0; j < 4; ++j) acc[i][j] = (f32x4){0.f, 0.f, 0.f, 0.f};

    // staging: wave w covers rows {w*16..+15} (+64 / +128 / +192 for B) of each operand;
    // lane l: row sub = l>>2, col seg (l&3)*16B -> one gl2lds16 = 16 rows x 64B contiguous.
    const int srow = w * 16 + (l >> 2);
    const int scol = (l & 3) * 8;
    const unsigned short* Asrc = A  + (size_t)(bm + srow) * K + scol;
    const unsigned short* Bsrc = Bt + (size_t)(bn + srow) * K + scol;

    #define STG1(tt, bb) do {                                                       \
        gl2lds16(Asrc + (size_t)(tt) * 32,                   &ldsA[bb][w*16][0]);   \
        gl2lds16(Asrc + (size_t)64*K  + (size_t)(tt) * 32,   &ldsA[bb][64 + w*16][0]); \
        gl2lds16(Bsrc + (size_t)(tt) * 32,                   &ldsB[bb][w*16][0]);   \
        gl2lds16(Bsrc + (size_t)64*K  + (size_t)(tt) * 32,   &ldsB[bb][64 + w*16][0]); } while (0)
    #define STG2(tt, bb) do {                                                       \
        gl2lds16(Bsrc + (size_t)128*K + (size_t)(tt) * 32,   &ldsB[bb][128 + w*16][0]); \
        gl2lds16(Bsrc + (size_t)192*K + (size_t)(tt) * 32,   &ldsB[bb][192 + w*16][0]); } while (0)

    const int nkt = K >> 5;
    STG1(0, 0); STG2(0, 0);      // tile 0 -> buf 0   (6 loads/wave)
    STG1(1, 1); STG2(1, 1);      // tile 1 -> buf 1   (6 loads/wave)

    for (int kt = 0; kt < nkt; ++kt) {
        // boundary: tile kt resident after this (6 newest loads = tile kt+1)
        if (kt + 1 < nkt) asm volatile("s_waitcnt vmcnt(6)" ::: "memory");
        else              asm volatile("s_waitcnt vmcnt(0)" ::: "memory");
        asm volatile("s_barrier" ::: "memory");

        const unsigned short (*bufA)[32] = ldsA[kt % 3];
        const unsigned short (*bufB)[32] = ldsB[kt % 3];
        const int nb = (kt + 2) % 3;
        const bool pf = (kt + 2 < nkt);

        bf16x8 bfr[4], afr[4];
        #pragma unroll
        for (int j = 0; j < 4; ++j) bfr[j] = *(const bf16x8*)&bufB[w * 64 + j * 16 + lm][lg * 8];
        #pragma unroll
        for (int i = 0; i < 4; ++i) afr[i] = *(const bf16x8*)&bufA[i * 16 + lm][lg * 8];
        if (pf) STG1(kt + 2, nb);
        #pragma unroll
        for (int i = 0; i < 4; ++i)
            #pragma unroll
            for (int j = 0; j < 4; ++j)
                acc[i][j] = __builtin_amdgcn_mfma_f32_16x16x32_bf16(afr[i], bfr[j], acc[i][j], 0, 0, 0);

        #pragma unroll
        for (int i = 0; i < 4; ++i) afr[i] = *(const bf16x8*)&bufA[(i + 4) * 16 + lm][lg * 8];
        if (pf) STG2(kt + 2, nb);
        #pragma unroll
        for (int i = 0; i < 4; ++i)
            #pragma unroll
            for (int j = 0; j < 4; ++j)
                acc[i + 4][j] = __builtin_amdgcn_mfma_f32_16x16x32_bf16(afr[i], bfr[j], acc[i + 4][j], 0, 0, 0);
        // boundary barrier at loop top protects buffer reuse
    }
    #undef STG1
    #undef STG2

    // C/D: col = lane&15, row = (lane>>4)*4 + reg
    const int lr4 = lg * 4;
    #pragma unroll
    for (int i = 0; i < 8; ++i) {
        #pragma unroll
        for (int j = 0; j < 4; ++j) {
            int row = bm + i * 16 + lr4;
            int col = bn + w * 64 + j * 16 + lm;
            #pragma unroll
            for (int jj = 0; jj < 4; ++jj) {
                if constexpr (CF32)
                    ((float*)Cp)[(size_t)(row + jj) * Nst + col] = acc[i][j][jj];
                else
                    ((unsigned short*)Cp)[(size_t)(row + jj) * Nst + col] = f2bf(acc[i][j][jj]);
            }
        }
    }
}

// ---------------------------------------------------------------------------
// RoPE in-place on a slab of qkv (row stride NQKV).
// ---------------------------------------------------------------------------
template<int LOG2H>
__global__ __launch_bounds__(256)
void rope_kernel(unsigned short* __restrict__ data, const int* __restrict__ positions)
{
    const int gid  = blockIdx.x * 256 + threadIdx.x;
    const int j    = gid & 63;
    const int hr   = gid >> 6;
    const int head = hr & ((1 << LOG2H) - 1);
    const int bs   = hr >> LOG2H;
    const float pos = (float)positions[bs];
    const float inv = expf(-0.14391156831f * (float)j);
    float s, c;
    sincosf(pos * inv, &s, &c);
    const size_t base = (size_t)bs * NQKV + head * HD_;
    const float x1 = bf2f(data[base + j]);
    const float x2 = bf2f(data[base + 64 + j]);
    data[base + j]      = f2bf(x1 * c - x2 * s);
    data[base + 64 + j] = f2bf(x2 * c + x1 * s);
}

// ---------------------------------------------------------------------------
// MFMA flash attention, swapped-QK^T in-register softmax (unchanged, passing).
// ---------------------------------------------------------------------------
__global__ __launch_bounds__(256)
void attn_kernel(const unsigned short* __restrict__ qkv,
                 const unsigned short* __restrict__ vt,
                 unsigned short* __restrict__ ao)
{
    constexpr int LDK = 136;
    constexpr int LDV = 72;
    __shared__ alignas(16) unsigned short k_s[64][LDK];
    __shared__ alignas(16) unsigned short v_t[128][LDV];
    __shared__ alignas(16) unsigned short p_s[4][16][LDV];

    const int t   = threadIdx.x;
    const int blk = blockIdx.x;
    const int sb  = 31 - (blk >> 6);
    const int pr  = blk & 63;
    const int qh  = pr >> 1;
    const int b   = pr & 1;
    const int kh  = qh >> 2;
    const int l   = t & 63, w = t >> 6;
    const int lm  = l & 15;
    const int lg  = l >> 4;
    const int lg4 = lg * 4;
    const int lko = lg * 8;
    const int wrow = w * 16 + lm;

    const unsigned short* vtb = vt + (size_t)(b * NH_ + kh) * HD_ * S_;

    bf16x8 qf[4];
    {
        const size_t qrow = (size_t)(b * S_ + sb * 64 + wrow) * NQKV + qh * HD_;
        #pragma unroll
        for (int kk = 0; kk < 4; ++kk)
            qf[kk] = *(const bf16x8*)(qkv + qrow + kk * 32 + lko);
    }

    f32x4 acc_o[8];
    #pragma unroll
    for (int i = 0; i < 8; ++i) acc_o[i] = (f32x4){0.f, 0.f, 0.f, 0.f};
    float mreg = -1e30f, lreg = 0.f;

    const float sm_scale = 0.08838834764831845f;

    for (int c = 0; c <= sb; ++c) {
        __syncthreads();
        {
            const int key = t >> 2, seg = t & 3;
            const size_t g = (size_t)(b * S_ + c * 64 + key) * NQKV + KOFF + kh * HD_ + seg * 32;
            const uint4* ksrc = (const uint4*)(qkv + g);
            #pragma unroll
            for (int i = 0; i < 4; ++i)
                *(uint4*)&k_s[key][seg * 32 + i * 8] = ksrc[i];
        }
        {
            const int h  = t >> 1;
            const int ko = (t & 1) * 32;
            const unsigned short* src = vtb + (size_t)h * S_ + c * 64 + ko;
            #pragma unroll
            for (int i = 0; i < 4; ++i)
                *(uint4*)&v_t[h][ko + i * 8] = *(const uint4*)(src + i * 8);
        }
        __syncthreads();

        f32x4 acc_s[4];
        #pragma unroll
        for (int t4 = 0; t4 < 4; ++t4) acc_s[t4] = (f32x4){0.f, 0.f, 0.f, 0.f};
        #pragma unroll
        for (int kk = 0; kk < 4; ++kk) {
            const bf16x8 qv = qf[kk];
            bf16x8 kf0 = *(const bf16x8*)&k_s[0 * 16 + lm][kk * 32 + lko];
            bf16x8 kf1 = *(const bf16x8*)&k_s[1 * 16 + lm][kk * 32 + lko];
            bf16x8 kf2 = *(const bf16x8*)&k_s[2 * 16 + lm][kk * 32 + lko];
            bf16x8 kf3 = *(const bf16x8*)&k_s[3 * 16 + lm][kk * 32 + lko];
            __builtin_amdgcn_s_setprio(1);
            acc_s[0] = __builtin_amdgcn_mfma_f32_16x16x32_bf16(kf0, qv, acc_s[0], 0, 0, 0);
            acc_s[1] = __builtin_amdgcn_mfma_f32_16x16x32_bf16(kf1, qv, acc_s[1], 0, 0, 0);
            acc_s[2] = __builtin_amdgcn_mfma_f32_16x16x32_bf16(kf2, qv, acc_s[2], 0, 0, 0);
            acc_s[3] = __builtin_amdgcn_mfma_f32_16x16x32_bf16(kf3, qv, acc_s[3], 0, 0, 0);
            __builtin_amdgcn_s_setprio(0);
        }

        const bool diag = (c == sb);
        float p[4][4];
        #pragma unroll
        for (int t4 = 0; t4 < 4; ++t4)
            #pragma unroll
            for (int r = 0; r < 4; ++r) {
                float s = acc_s[t4][r] * sm_scale;
                if (diag && (t4 * 16 + lg4 + r > wrow)) s = -1e30f;
                p[t4][r] = s;
            }
        float mc = p[0][0];
        #pragma unroll
        for (int t4 = 0; t4 < 4; ++t4)
            #pragma unroll
            for (int r = 0; r < 4; ++r) mc = fmaxf(mc, p[t4][r]);
        mc = fmaxf(mc, __shfl_xor(mc, 16, 64));
        mc = fmaxf(mc, __shfl_xor(mc, 32, 64));
        float sf = 1.0f;
        if (mc > mreg + 8.0f) {
            sf = __expf(mreg - mc);
            mreg = mc;
            lreg *= sf;
        }
        if (__any(sf != 1.0f)) {
            #pragma unroll
            for (int r = 0; r < 4; ++r) {
                const float s_r = __shfl(sf, (l & 48) | (lg4 + r), 64);
                #pragma unroll
                for (int ht = 0; ht < 8; ++ht) acc_o[ht][r] *= s_r;
            }
        }
        float ps = 0.f;
        #pragma unroll
        for (int t4 = 0; t4 < 4; ++t4)
            #pragma unroll
            for (int r = 0; r < 4; ++r) {
                p[t4][r] = __expf(p[t4][r] - mreg);
                ps += p[t4][r];
            }
        ps += __shfl_xor(ps, 16, 64);
        ps += __shfl_xor(ps, 32, 64);
        lreg += ps;
        #pragma unroll
        for (int t4 = 0; t4 < 4; ++t4) {
            unsigned int d0 = (unsigned int)f2bf(p[t4][0]) | ((unsigned int)f2bf(p[t4][1]) << 16);
            unsigned int d1 = (unsigned int)f2bf(p[t4][2]) | ((unsigned int)f2bf(p[t4][3]) << 16);
            *(unsigned int*)&p_s[w][lm][t4 * 16 + lg4]     = d0;
            *(unsigned int*)&p_s[w][lm][t4 * 16 + lg4 + 2] = d1;
        }

        #pragma unroll
        for (int kk = 0; kk < 2; ++kk) {
            const bf16x8 pa = *(const bf16x8*)&p_s[w][lm][kk * 32 + lko];
            #pragma unroll
            for (int ht = 0; ht < 8; ht += 4) {
                bf16x8 bv0 = *(const bf16x8*)&v_t[(ht + 0) * 16 + lm][kk * 32 + lko];
                bf16x8 bv1 = *(const bf16x8*)&v_t[(ht + 1) * 16 + lm][kk * 32 + lko];
                bf16x8 bv2 = *(const bf16x8*)&v_t[(ht + 2) * 16 + lm][kk * 32 + lko];
                bf16x8 bv3 = *(const bf16x8*)&v_t[(ht + 3) * 16 + lm][kk * 32 + lko];
                __builtin_amdgcn_s_setprio(1);
                acc_o[ht + 0] = __builtin_amdgcn_mfma_f32_16x16x32_bf16(pa, bv0, acc_o[ht + 0], 0, 0, 0);
                acc_o[ht + 1] = __builtin_amdgcn_mfma_f32_16x16x32_bf16(pa, bv1, acc_o[ht + 1], 0, 0, 0);
                acc_o[ht + 2] = __builtin_amdgcn_mfma_f32_16x16x32_bf16(pa, bv2, acc_o[ht + 2], 0, 0, 0);
                acc_o[ht + 3] = __builtin_amdgcn_mfma_f32_16x16x32_bf16(pa, bv3, acc_o[ht + 3], 0, 0, 0);
                __builtin_amdgcn_s_setprio(0);
            }
        }
    }

    #pragma unroll
    for (int r = 0; r < 4; ++r) {
        const float lr = __shfl(lreg, (l & 48) | (lg4 + r), 64);
        const float invl = 1.f / lr;
        const size_t row = (size_t)(b * S_ + sb * 64 + w * 16 + lg4 + r);
        #pragma unroll
        for (int ht = 0; ht < 8; ++ht)
            ao[(row * QH_ + qh) * HD_ + ht * 16 + lm] = f2bf(acc_o[ht][r] * invl);
    }
}

// ---------------------------------------------------------------------------
extern "C" void kernel_launch(void* const* d_in, const int* in_sizes, int n_in,
                              void* d_out, int out_size, void* d_ws, size_t ws_size,
                              hipStream_t stream)
{
    const float* x  = (const float*)d_in[0];
    const int*  pos = (const int*)d_in[1];
    const float* Wq = (const float*)d_in[2];
    const float* Wk = (const float*)d_in[3];
    const float* Wv = (const float*)d_in[4];
    const float* Wo = (const float*)d_in[5];
    float* out = (float*)d_out;

    char* wsb = (char*)d_ws;
    unsigned short* qkv = (unsigned short*)(wsb);              // 48 MiB [4096][6144]
    unsigned short* wt  = (unsigned short*)(wsb + 50331648);   // Wt_qkv 48M -> Wt_o 32M
    unsigned short* vt  = (unsigned short*)(wsb + 83886080);   // 8 MiB V^T
    unsigned short* r0  = (unsigned short*)(wsb + 100663296);  // 32 MiB x_bf -> ao

    const dim3 blk(256);
    convert_bf16_kernel<<<8192, blk, 0, stream>>>(x, r0);
    transpose_conv_kernel<<<dim3(2, 64, 32), blk, 0, stream>>>(Wq, wt, D_, HD_);
    transpose_conv_kernel<<<dim3(2, 64, 8),  blk, 0, stream>>>(Wk, wt + (size_t)KOFF * D_, D_, HD_);
    transpose_conv_kernel<<<dim3(2, 64, 8),  blk, 0, stream>>>(Wv, wt + (size_t)VOFF * D_, D_, HD_);
    // fused QKV projection: grid 24x32 = 768 blocks = 3.0 rounds
    gemm128_kernel<0><<<dim3(NQKV / 256, MROWS / 128), blk, 0, stream>>>(r0, wt, qkv, NQKV, D_);
    transpose_conv_kernel<<<dim3(64, 64, 1), blk, 0, stream>>>(Wo, wt, D_, D_);
    transpose_v_kernel<<<dim3(2, 32, 16), blk, 0, stream>>>(qkv, vt);
    rope_kernel<5><<<(MROWS * QH_ * 64) / 256, blk, 0, stream>>>(qkv, pos);
    rope_kernel<3><<<(MROWS * NH_ * 64) / 256, blk, 0, stream>>>(qkv + KOFF, pos);
    attn_kernel<<<B_ * QH_ * (S_ / 64), blk, 0, stream>>>(qkv, vt, r0);
    // output projection: grid 16x32 = 512 blocks = 2.0 rounds
    gemm128_kernel<1><<<dim3(D_ / 256, MROWS / 128), blk, 0, stream>>>(r0, wt, out, D_, QH_ * HD_);
}

// Round 10
// 584.259 us; speedup vs baseline: 1.1465x; 1.1465x over previous
//
#include <hip/hip_runtime.h>
#include <cstdint>
#include <cstddef>

#define B_  2
#define S_  2048
#define D_  4096
#define QH_ 32
#define NH_ 8
#define HD_ 128
#define MROWS (B_ * S_)                      // 4096
#define NQKV  (QH_ * HD_ + 2 * NH_ * HD_)    // 6144
#define KOFF  (QH_ * HD_)                    // 4096
#define VOFF  (QH_ * HD_ + NH_ * HD_)        // 5120

typedef __attribute__((ext_vector_type(8))) short bf16x8;
typedef __attribute__((ext_vector_type(4))) float f32x4;

__device__ __forceinline__ unsigned short f2bf(float f) {
    unsigned int u = __float_as_uint(f);
    return (unsigned short)((u + 0x7FFFu + ((u >> 16) & 1u)) >> 16);
}
__device__ __forceinline__ float bf2f(unsigned short h) { return __uint_as_float(((unsigned int)h) << 16); }

__device__ __forceinline__ void gl2lds16(const void* g, void* l) {
    __builtin_amdgcn_global_load_lds(
        (const __attribute__((address_space(1))) void*)g,
        (__attribute__((address_space(3))) void*)l, 16, 0, 0);
}

// ---------------------------------------------------------------------------
// fp32 -> bf16 straight convert (x). 8 elems/thread.
// ---------------------------------------------------------------------------
__global__ __launch_bounds__(256)
void convert_bf16_kernel(const float* __restrict__ in, unsigned short* __restrict__ out)
{
    const size_t i = ((size_t)blockIdx.x * 256 + threadIdx.x) * 8;
    float4 a = *(const float4*)(in + i);
    float4 b = *(const float4*)(in + i + 4);
    uint4 o;
    o.x = (unsigned int)f2bf(a.x) | ((unsigned int)f2bf(a.y) << 16);
    o.y = (unsigned int)f2bf(a.z) | ((unsigned int)f2bf(a.w) << 16);
    o.z = (unsigned int)f2bf(b.x) | ((unsigned int)f2bf(b.y) << 16);
    o.w = (unsigned int)f2bf(b.z) | ((unsigned int)f2bf(b.w) << 16);
    *(uint4*)(out + i) = o;
}

// ---------------------------------------------------------------------------
// Tile transpose-convert: in fp32 [R][C] (slab z) -> out bf16 [C][R]
// ---------------------------------------------------------------------------
__global__ __launch_bounds__(256)
void transpose_conv_kernel(const float* __restrict__ in, unsigned short* __restrict__ out,
                           int R, int C)
{
    __shared__ unsigned short tile[64][72];
    const int t  = threadIdx.x;
    const int c0 = blockIdx.x * 64;
    const int r0 = blockIdx.y * 64;
    in  += (size_t)blockIdx.z * R * C;
    out += (size_t)blockIdx.z * R * C;
    {
        const int rr = t >> 4;
        const int cc = (t & 15) * 4;
        #pragma unroll
        for (int p = 0; p < 4; ++p) {
            float4 v = *(const float4*)(in + (size_t)(r0 + p * 16 + rr) * C + c0 + cc);
            unsigned int lo = (unsigned int)f2bf(v.x) | ((unsigned int)f2bf(v.y) << 16);
            unsigned int hi = (unsigned int)f2bf(v.z) | ((unsigned int)f2bf(v.w) << 16);
            *(uint2*)&tile[p * 16 + rr][cc] = make_uint2(lo, hi);
        }
    }
    __syncthreads();
    {
        const int j  = t >> 3;
        const int i8 = (t & 7) * 8;
        #pragma unroll
        for (int p = 0; p < 2; ++p) {
            unsigned short tmp[8];
            #pragma unroll
            for (int e = 0; e < 8; ++e) tmp[e] = tile[i8 + e][p * 32 + j];
            *(uint4*)(out + (size_t)(c0 + p * 32 + j) * R + r0 + i8) = *(uint4*)tmp;
        }
    }
}

// ---------------------------------------------------------------------------
// bf16 transpose of the V slab of qkv: -> vt[(b*8+kh)*128 + h][2048 s]
// ---------------------------------------------------------------------------
__global__ __launch_bounds__(256)
void transpose_v_kernel(const unsigned short* __restrict__ qkv, unsigned short* __restrict__ vt)
{
    __shared__ unsigned short tile[64][76];
    const int t  = threadIdx.x;
    const int z  = blockIdx.z;            // b*8+kh
    const int b  = z >> 3, kh = z & 7;
    const int h0 = blockIdx.x * 64;
    const int s0 = blockIdx.y * 64;
    const unsigned short* in = qkv + (size_t)(b * S_) * NQKV + VOFF + kh * HD_;
    unsigned short* outb = vt + (size_t)z * HD_ * S_;
    {
        const int rr = t >> 4;            // s-local
        const int cc = (t & 15) * 4;      // h-local
        #pragma unroll
        for (int p = 0; p < 4; ++p) {
            uint2 v = *(const uint2*)(in + (size_t)(s0 + p * 16 + rr) * NQKV + h0 + cc);
            *(uint2*)&tile[p * 16 + rr][cc] = v;
        }
    }
    __syncthreads();
    {
        const int j  = t >> 3;            // h-local 0..31
        const int i8 = (t & 7) * 8;       // s-local
        #pragma unroll
        for (int p = 0; p < 2; ++p) {
            unsigned short tmp[8];
            #pragma unroll
            for (int e = 0; e < 8; ++e) tmp[e] = tile[i8 + e][p * 32 + j];
            *(uint4*)(outb + (size_t)(h0 + p * 32 + j) * S_ + s0 + i8) = *(uint4*)tmp;
        }
    }
}

// ---------------------------------------------------------------------------
// 256x256 GEMM, BK=32, triple-buffered (96 KiB), ONE barrier + ONE counted
// vmcnt(4) gate per K-tile (never 0 in-loop). Round-8 proven config (236 us
// QKV, ~873 TF). Staging of tile kt+2 issued inside tile kt. WAR proof:
// buffer (kt+2)%3 last read in tile kt-1, finished by all waves before tile
// kt's boundary barrier.
// ---------------------------------------------------------------------------
template<int CF32>
__global__ __launch_bounds__(512, 2)
void gemm256_kernel(const unsigned short* __restrict__ A,
                    const unsigned short* __restrict__ Bt,
                    void* __restrict__ Cp, int Nst, int K)
{
    __shared__ alignas(16) unsigned short lds[3][2][256][32];  // 96 KiB

    const int t = threadIdx.x, l = t & 63, w = t >> 6;
    const int gx  = gridDim.x;
    const int nwg = gx * gridDim.y;
    int lin = blockIdx.y * gx + blockIdx.x;
    lin = (lin & 7) * (nwg >> 3) + (lin >> 3);       // bijective XCD swizzle (nwg%8==0)
    const int bn = (lin % gx) * 256, bm = (lin / gx) * 256;
    const int wr = w >> 2, wc = w & 3;               // 2 (M) x 4 (N) waves
    const int lm = l & 15, lg = l >> 4;

    f32x4 acc[8][4];
    #pragma unroll
    for (int i = 0; i < 8; ++i)
        #pragma unroll
        for (int j = 0; j < 4; ++j) acc[i][j] = (f32x4){0.f, 0.f, 0.f, 0.f};

    const int srow = w * 16 + (l >> 2);
    const int scol = (l & 3) * 8;
    const unsigned short* Asrc = A  + (size_t)(bm + srow) * K + scol;
    const unsigned short* Bsrc = Bt + (size_t)(bn + srow) * K + scol;

    #define STAGE_A(tt, bb) do {                                                  \
        gl2lds16(Asrc + (size_t)(tt) * 32,                  &lds[bb][0][w*16][0]); \
        gl2lds16(Asrc + (size_t)128*K + (size_t)(tt) * 32,  &lds[bb][0][128 + w*16][0]); } while (0)
    #define STAGE_B(tt, bb) do {                                                  \
        gl2lds16(Bsrc + (size_t)(tt) * 32,                  &lds[bb][1][w*16][0]); \
        gl2lds16(Bsrc + (size_t)128*K + (size_t)(tt) * 32,  &lds[bb][1][128 + w*16][0]); } while (0)

    const int nkt = K >> 5;
    STAGE_A(0, 0); STAGE_B(0, 0);
    STAGE_A(1, 1); STAGE_B(1, 1);

    for (int kt = 0; kt < nkt; ++kt) {
        if (kt + 1 < nkt) asm volatile("s_waitcnt vmcnt(4)" ::: "memory");
        else              asm volatile("s_waitcnt vmcnt(0)" ::: "memory");
        asm volatile("s_barrier" ::: "memory");

        const unsigned short (*bufA)[32] = lds[kt % 3][0];
        const unsigned short (*bufB)[32] = lds[kt % 3][1];
        const int nb = (kt + 2) % 3;
        const bool pf = (kt + 2 < nkt);

        bf16x8 bfr[4], afr[4];
        #pragma unroll
        for (int j = 0; j < 4; ++j) bfr[j] = *(const bf16x8*)&bufB[wc * 64 + j * 16 + lm][lg * 8];
        #pragma unroll
        for (int i = 0; i < 4; ++i) afr[i] = *(const bf16x8*)&bufA[wr * 128 + i * 16 + lm][lg * 8];
        if (pf) STAGE_A(kt + 2, nb);
        #pragma unroll
        for (int i = 0; i < 4; ++i)
            #pragma unroll
            for (int j = 0; j < 4; ++j)
                acc[i][j] = __builtin_amdgcn_mfma_f32_16x16x32_bf16(afr[i], bfr[j], acc[i][j], 0, 0, 0);

        #pragma unroll
        for (int i = 0; i < 4; ++i) afr[i] = *(const bf16x8*)&bufA[wr * 128 + (i + 4) * 16 + lm][lg * 8];
        if (pf) STAGE_B(kt + 2, nb);
        #pragma unroll
        for (int i = 0; i < 4; ++i)
            #pragma unroll
            for (int j = 0; j < 4; ++j)
                acc[i + 4][j] = __builtin_amdgcn_mfma_f32_16x16x32_bf16(afr[i], bfr[j], acc[i + 4][j], 0, 0, 0);
    }
    #undef STAGE_A
    #undef STAGE_B

    const int lr4 = lg * 4;
    #pragma unroll
    for (int i = 0; i < 8; ++i) {
        #pragma unroll
        for (int j = 0; j < 4; ++j) {
            int row = bm + wr * 128 + i * 16 + lr4;
            int col = bn + wc * 64 + j * 16 + lm;
            #pragma unroll
            for (int jj = 0; jj < 4; ++jj) {
                if constexpr (CF32)
                    ((float*)Cp)[(size_t)(row + jj) * Nst + col] = acc[i][j][jj];
                else
                    ((unsigned short*)Cp)[(size_t)(row + jj) * Nst + col] = f2bf(acc[i][j][jj]);
            }
        }
    }
}

// ---------------------------------------------------------------------------
// RoPE in-place on a slab of qkv (row stride NQKV).
// ---------------------------------------------------------------------------
template<int LOG2H>
__global__ __launch_bounds__(256)
void rope_kernel(unsigned short* __restrict__ data, const int* __restrict__ positions)
{
    const int gid  = blockIdx.x * 256 + threadIdx.x;
    const int j    = gid & 63;
    const int hr   = gid >> 6;
    const int head = hr & ((1 << LOG2H) - 1);
    const int bs   = hr >> LOG2H;
    const float pos = (float)positions[bs];
    const float inv = expf(-0.14391156831f * (float)j);
    float s, c;
    sincosf(pos * inv, &s, &c);
    const size_t base = (size_t)bs * NQKV + head * HD_;
    const float x1 = bf2f(data[base + j]);
    const float x2 = bf2f(data[base + 64 + j]);
    data[base + j]      = f2bf(x1 * c - x2 * s);
    data[base + 64 + j] = f2bf(x2 * c + x1 * s);
}

// ---------------------------------------------------------------------------
// MFMA flash attention, swapped-QK^T in-register softmax.
// NEW (round 10): K/V staged via global_load_lds into DOUBLE-BUFFERED linear
// LDS with additive rotate swizzle (both sides, rule 21):
//   LDS[row][b] = G[row][(b + (row&7)*16B) mod rowbytes]   (pre-rotated
//   per-lane GLOBAL source; LDS dest linear as gl2lds requires)
//   read byte  = (g - (row&7)*16B) mod rowbytes
// Bank check: slot8 = (kk*4+lg-lm) mod 8 -> 2 lanes/slot = free (m136).
// Stage(c+1) issued right after the single per-chunk __syncthreads (T14):
// its vmcnt(0) is the gate for chunk c (loads issued one compute phase ago,
// latency hidden); WAR safe: buffer (c+1)&1 last read in chunk c-1, all
// waves passed this barrier after finishing those reads.
// ---------------------------------------------------------------------------
__global__ __launch_bounds__(256)
void attn_kernel(const unsigned short* __restrict__ qkv,
                 const unsigned short* __restrict__ vt,
                 unsigned short* __restrict__ ao)
{
    __shared__ alignas(16) unsigned short k_s[2][64][128];   // 32 KiB
    __shared__ alignas(16) unsigned short v_t[2][128][64];   // 32 KiB
    __shared__ alignas(16) unsigned short p_s[4][16][72];    // 9 KiB

    const int t   = threadIdx.x;
    const int blk = blockIdx.x;
    const int sb  = 31 - (blk >> 6);     // heavy (sb=31) blocks launch first
    const int pr  = blk & 63;
    const int qh  = pr >> 1;
    const int b   = pr & 1;
    const int kh  = qh >> 2;
    const int l   = t & 63, w = t >> 6;
    const int lm  = l & 15;
    const int lg  = l >> 4;
    const int lg4 = lg * 4;
    const int lko = lg * 8;
    const int wrow = w * 16 + lm;
    const int rot  = (lm & 7) * 8;       // read-side rotation (elems)

    const unsigned short* vtb = vt + (size_t)(b * NH_ + kh) * HD_ * S_;
    const size_t kvrow0 = (size_t)(b * S_) * NQKV + KOFF + kh * HD_;

    // swizzled read cols (precomputed, lane-constant)
    int ck[4], cv[2];
    #pragma unroll
    for (int kk = 0; kk < 4; ++kk) ck[kk] = (kk * 32 + lko - rot) & 127;
    #pragma unroll
    for (int kk = 0; kk < 2; ++kk) cv[kk] = (kk * 32 + lko - rot) & 63;

    // K stage: 4 gl2lds/thread, rows w*16+i*4+(l>>4); source pre-rotated
    // V stage: 4 gl2lds/thread, rows w*32+i*8+(l>>3); source pre-rotated
    const int krsub = l >> 4, ksseg = (l & 15) * 8;
    const int vrsub = l >> 3, vsseg = (l & 7) * 8;
    #define STAGEKV(cc, bb) do {                                                   \
        const int c64_ = (cc) * 64;                                                \
        _Pragma("unroll")                                                          \
        for (int i_ = 0; i_ < 4; ++i_) {                                           \
            const int kr_ = w * 16 + i_ * 4 + krsub;                               \
            const int ko_ = (ksseg + ((kr_ & 7) << 3)) & 127;                      \
            gl2lds16(qkv + kvrow0 + (size_t)(c64_ + kr_) * NQKV + ko_,             \
                     &k_s[bb][w * 16 + i_ * 4][0]);                                \
        }                                                                          \
        _Pragma("unroll")                                                          \
        for (int i_ = 0; i_ < 4; ++i_) {                                           \
            const int hv_ = w * 32 + i_ * 8 + vrsub;                               \
            const int vo_ = (vsseg + ((hv_ & 7) << 3)) & 63;                       \
            gl2lds16(vtb + (size_t)hv_ * S_ + c64_ + vo_,                          \
                     &v_t[bb][w * 32 + i_ * 8][0]);                                \
        }                                                                          \
    } while (0)

    bf16x8 qf[4];
    {
        const size_t qrow = (size_t)(b * S_ + sb * 64 + wrow) * NQKV + qh * HD_;
        #pragma unroll
        for (int kk = 0; kk < 4; ++kk)
            qf[kk] = *(const bf16x8*)(qkv + qrow + kk * 32 + lko);
    }

    f32x4 acc_o[8];
    #pragma unroll
    for (int i = 0; i < 8; ++i) acc_o[i] = (f32x4){0.f, 0.f, 0.f, 0.f};
    float mreg = -1e30f, lreg = 0.f;

    const float sm_scale = 0.08838834764831845f;

    STAGEKV(0, 0);   // prologue: chunk 0 -> buffer 0

    for (int c = 0; c <= sb; ++c) {
        const int cur = c & 1;
        __syncthreads();                 // vmcnt(0)+lgkmcnt(0)+barrier: chunk c ready
        if (c < sb) STAGEKV(c + 1, cur ^ 1);

        // ---- QK^T swapped: acc_s[t4][r] = S[key=t4*16+lg4+r][qrow=wrow] ----
        f32x4 acc_s[4];
        #pragma unroll
        for (int t4 = 0; t4 < 4; ++t4) acc_s[t4] = (f32x4){0.f, 0.f, 0.f, 0.f};
        #pragma unroll
        for (int kk = 0; kk < 4; ++kk) {
            const bf16x8 qv = qf[kk];
            bf16x8 kf0 = *(const bf16x8*)&k_s[cur][0 * 16 + lm][ck[kk]];
            bf16x8 kf1 = *(const bf16x8*)&k_s[cur][1 * 16 + lm][ck[kk]];
            bf16x8 kf2 = *(const bf16x8*)&k_s[cur][2 * 16 + lm][ck[kk]];
            bf16x8 kf3 = *(const bf16x8*)&k_s[cur][3 * 16 + lm][ck[kk]];
            __builtin_amdgcn_s_setprio(1);
            acc_s[0] = __builtin_amdgcn_mfma_f32_16x16x32_bf16(kf0, qv, acc_s[0], 0, 0, 0);
            acc_s[1] = __builtin_amdgcn_mfma_f32_16x16x32_bf16(kf1, qv, acc_s[1], 0, 0, 0);
            acc_s[2] = __builtin_amdgcn_mfma_f32_16x16x32_bf16(kf2, qv, acc_s[2], 0, 0, 0);
            acc_s[3] = __builtin_amdgcn_mfma_f32_16x16x32_bf16(kf3, qv, acc_s[3], 0, 0, 0);
            __builtin_amdgcn_s_setprio(0);
        }

        // ---- in-register online softmax (defer-max THR=8) ----
        const bool diag = (c == sb);
        float p[4][4];
        #pragma unroll
        for (int t4 = 0; t4 < 4; ++t4)
            #pragma unroll
            for (int r = 0; r < 4; ++r) {
                float s = acc_s[t4][r] * sm_scale;
                if (diag && (t4 * 16 + lg4 + r > wrow)) s = -1e30f;
                p[t4][r] = s;
            }
        float mc = p[0][0];
        #pragma unroll
        for (int t4 = 0; t4 < 4; ++t4)
            #pragma unroll
            for (int r = 0; r < 4; ++r) mc = fmaxf(mc, p[t4][r]);
        mc = fmaxf(mc, __shfl_xor(mc, 16, 64));
        mc = fmaxf(mc, __shfl_xor(mc, 32, 64));
        float sf = 1.0f;
        if (mc > mreg + 8.0f) {
            sf = __expf(mreg - mc);
            mreg = mc;
            lreg *= sf;
        }
        if (__any(sf != 1.0f)) {
            #pragma unroll
            for (int r = 0; r < 4; ++r) {
                const float s_r = __shfl(sf, (l & 48) | (lg4 + r), 64);
                #pragma unroll
                for (int ht = 0; ht < 8; ++ht) acc_o[ht][r] *= s_r;
            }
        }
        float ps = 0.f;
        #pragma unroll
        for (int t4 = 0; t4 < 4; ++t4)
            #pragma unroll
            for (int r = 0; r < 4; ++r) {
                p[t4][r] = __expf(p[t4][r] - mreg);
                ps += p[t4][r];
            }
        ps += __shfl_xor(ps, 16, 64);
        ps += __shfl_xor(ps, 32, 64);
        lreg += ps;
        #pragma unroll
        for (int t4 = 0; t4 < 4; ++t4) {
            unsigned int d0 = (unsigned int)f2bf(p[t4][0]) | ((unsigned int)f2bf(p[t4][1]) << 16);
            unsigned int d1 = (unsigned int)f2bf(p[t4][2]) | ((unsigned int)f2bf(p[t4][3]) << 16);
            *(unsigned int*)&p_s[w][lm][t4 * 16 + lg4]     = d0;
            *(unsigned int*)&p_s[w][lm][t4 * 16 + lg4 + 2] = d1;
        }

        // ---- PV ----
        #pragma unroll
        for (int kk = 0; kk < 2; ++kk) {
            const bf16x8 pa = *(const bf16x8*)&p_s[w][lm][kk * 32 + lko];
            #pragma unroll
            for (int ht = 0; ht < 8; ht += 4) {
                bf16x8 bv0 = *(const bf16x8*)&v_t[cur][(ht + 0) * 16 + lm][cv[kk]];
                bf16x8 bv1 = *(const bf16x8*)&v_t[cur][(ht + 1) * 16 + lm][cv[kk]];
                bf16x8 bv2 = *(const bf16x8*)&v_t[cur][(ht + 2) * 16 + lm][cv[kk]];
                bf16x8 bv3 = *(const bf16x8*)&v_t[cur][(ht + 3) * 16 + lm][cv[kk]];
                __builtin_amdgcn_s_setprio(1);
                acc_o[ht + 0] = __builtin_amdgcn_mfma_f32_16x16x32_bf16(pa, bv0, acc_o[ht + 0], 0, 0, 0);
                acc_o[ht + 1] = __builtin_amdgcn_mfma_f32_16x16x32_bf16(pa, bv1, acc_o[ht + 1], 0, 0, 0);
                acc_o[ht + 2] = __builtin_amdgcn_mfma_f32_16x16x32_bf16(pa, bv2, acc_o[ht + 2], 0, 0, 0);
                acc_o[ht + 3] = __builtin_amdgcn_mfma_f32_16x16x32_bf16(pa, bv3, acc_o[ht + 3], 0, 0, 0);
                __builtin_amdgcn_s_setprio(0);
            }
        }
    }
    #undef STAGEKV

    #pragma unroll
    for (int r = 0; r < 4; ++r) {
        const float lr = __shfl(lreg, (l & 48) | (lg4 + r), 64);
        const float invl = 1.f / lr;
        const size_t row = (size_t)(b * S_ + sb * 64 + w * 16 + lg4 + r);
        #pragma unroll
        for (int ht = 0; ht < 8; ++ht)
            ao[(row * QH_ + qh) * HD_ + ht * 16 + lm] = f2bf(acc_o[ht][r] * invl);
    }
}

// ---------------------------------------------------------------------------
extern "C" void kernel_launch(void* const* d_in, const int* in_sizes, int n_in,
                              void* d_out, int out_size, void* d_ws, size_t ws_size,
                              hipStream_t stream)
{
    const float* x  = (const float*)d_in[0];
    const int*  pos = (const int*)d_in[1];
    const float* Wq = (const float*)d_in[2];
    const float* Wk = (const float*)d_in[3];
    const float* Wv = (const float*)d_in[4];
    const float* Wo = (const float*)d_in[5];
    float* out = (float*)d_out;

    char* wsb = (char*)d_ws;
    unsigned short* qkv = (unsigned short*)(wsb);              // 48 MiB [4096][6144]
    unsigned short* wt  = (unsigned short*)(wsb + 50331648);   // Wt_qkv 48M -> Wt_o 32M
    unsigned short* vt  = (unsigned short*)(wsb + 83886080);   // V^T
    unsigned short* r0  = (unsigned short*)(wsb + 100663296);  // 32 MiB x_bf -> ao

    const dim3 blk(256);
    const dim3 blk512(512);
    convert_bf16_kernel<<<8192, blk, 0, stream>>>(x, r0);
    transpose_conv_kernel<<<dim3(2, 64, 32), blk, 0, stream>>>(Wq, wt, D_, HD_);
    transpose_conv_kernel<<<dim3(2, 64, 8),  blk, 0, stream>>>(Wk, wt + (size_t)KOFF * D_, D_, HD_);
    transpose_conv_kernel<<<dim3(2, 64, 8),  blk, 0, stream>>>(Wv, wt + (size_t)VOFF * D_, D_, HD_);
    gemm256_kernel<0><<<dim3(NQKV / 256, MROWS / 256), blk512, 0, stream>>>(r0, wt, qkv, NQKV, D_);
    transpose_conv_kernel<<<dim3(64, 64, 1), blk, 0, stream>>>(Wo, wt, D_, D_);
    transpose_v_kernel<<<dim3(2, 32, 16), blk, 0, stream>>>(qkv, vt);
    rope_kernel<5><<<(MROWS * QH_ * 64) / 256, blk, 0, stream>>>(qkv, pos);
    rope_kernel<3><<<(MROWS * NH_ * 64) / 256, blk, 0, stream>>>(qkv + KOFF, pos);
    attn_kernel<<<B_ * QH_ * (S_ / 64), blk, 0, stream>>>(qkv, vt, r0);
    gemm256_kernel<1><<<dim3(D_ / 256, MROWS / 256), blk512, 0, stream>>>(r0, wt, out, D_, QH_ * HD_);
}

// Round 11
// 574.034 us; speedup vs baseline: 1.1669x; 1.0178x over previous
//
#include <hip/hip_runtime.h>
#include <cstdint>
#include <cstddef>

#define B_  2
#define S_  2048
#define D_  4096
#define QH_ 32
#define NH_ 8
#define HD_ 128
#define MROWS (B_ * S_)                      // 4096
#define NQKV  (QH_ * HD_ + 2 * NH_ * HD_)    // 6144
#define KOFF  (QH_ * HD_)                    // 4096
#define VOFF  (QH_ * HD_ + NH_ * HD_)        // 5120

typedef __attribute__((ext_vector_type(8))) short bf16x8;
typedef __attribute__((ext_vector_type(4))) float f32x4;

__device__ __forceinline__ unsigned short f2bf(float f) {
    unsigned int u = __float_as_uint(f);
    return (unsigned short)((u + 0x7FFFu + ((u >> 16) & 1u)) >> 16);
}
__device__ __forceinline__ float bf2f(unsigned short h) { return __uint_as_float(((unsigned int)h) << 16); }

__device__ __forceinline__ void gl2lds16(const void* g, void* l) {
    __builtin_amdgcn_global_load_lds(
        (const __attribute__((address_space(1))) void*)g,
        (__attribute__((address_space(3))) void*)l, 16, 0, 0);
}

// ---------------------------------------------------------------------------
// fp32 -> bf16 straight convert (x). 8 elems/thread.
// ---------------------------------------------------------------------------
__global__ __launch_bounds__(256)
void convert_bf16_kernel(const float* __restrict__ in, unsigned short* __restrict__ out)
{
    const size_t i = ((size_t)blockIdx.x * 256 + threadIdx.x) * 8;
    float4 a = *(const float4*)(in + i);
    float4 b = *(const float4*)(in + i + 4);
    uint4 o;
    o.x = (unsigned int)f2bf(a.x) | ((unsigned int)f2bf(a.y) << 16);
    o.y = (unsigned int)f2bf(a.z) | ((unsigned int)f2bf(a.w) << 16);
    o.z = (unsigned int)f2bf(b.x) | ((unsigned int)f2bf(b.y) << 16);
    o.w = (unsigned int)f2bf(b.z) | ((unsigned int)f2bf(b.w) << 16);
    *(uint4*)(out + i) = o;
}

// ---------------------------------------------------------------------------
// Tile transpose-convert: in fp32 [R][C] (slab z) -> out bf16 [C][R]
// ---------------------------------------------------------------------------
__global__ __launch_bounds__(256)
void transpose_conv_kernel(const float* __restrict__ in, unsigned short* __restrict__ out,
                           int R, int C)
{
    __shared__ unsigned short tile[64][72];
    const int t  = threadIdx.x;
    const int c0 = blockIdx.x * 64;
    const int r0 = blockIdx.y * 64;
    in  += (size_t)blockIdx.z * R * C;
    out += (size_t)blockIdx.z * R * C;
    {
        const int rr = t >> 4;
        const int cc = (t & 15) * 4;
        #pragma unroll
        for (int p = 0; p < 4; ++p) {
            float4 v = *(const float4*)(in + (size_t)(r0 + p * 16 + rr) * C + c0 + cc);
            unsigned int lo = (unsigned int)f2bf(v.x) | ((unsigned int)f2bf(v.y) << 16);
            unsigned int hi = (unsigned int)f2bf(v.z) | ((unsigned int)f2bf(v.w) << 16);
            *(uint2*)&tile[p * 16 + rr][cc] = make_uint2(lo, hi);
        }
    }
    __syncthreads();
    {
        const int j  = t >> 3;
        const int i8 = (t & 7) * 8;
        #pragma unroll
        for (int p = 0; p < 2; ++p) {
            unsigned short tmp[8];
            #pragma unroll
            for (int e = 0; e < 8; ++e) tmp[e] = tile[i8 + e][p * 32 + j];
            *(uint4*)(out + (size_t)(c0 + p * 32 + j) * R + r0 + i8) = *(uint4*)tmp;
        }
    }
}

// ---------------------------------------------------------------------------
// bf16 transpose of the V slab of qkv: -> vt[(b*8+kh)*128 + h][2048 s]
// ---------------------------------------------------------------------------
__global__ __launch_bounds__(256)
void transpose_v_kernel(const unsigned short* __restrict__ qkv, unsigned short* __restrict__ vt)
{
    __shared__ unsigned short tile[64][76];
    const int t  = threadIdx.x;
    const int z  = blockIdx.z;            // b*8+kh
    const int b  = z >> 3, kh = z & 7;
    const int h0 = blockIdx.x * 64;
    const int s0 = blockIdx.y * 64;
    const unsigned short* in = qkv + (size_t)(b * S_) * NQKV + VOFF + kh * HD_;
    unsigned short* outb = vt + (size_t)z * HD_ * S_;
    {
        const int rr = t >> 4;            // s-local
        const int cc = (t & 15) * 4;      // h-local
        #pragma unroll
        for (int p = 0; p < 4; ++p) {
            uint2 v = *(const uint2*)(in + (size_t)(s0 + p * 16 + rr) * NQKV + h0 + cc);
            *(uint2*)&tile[p * 16 + rr][cc] = v;
        }
    }
    __syncthreads();
    {
        const int j  = t >> 3;            // h-local 0..31
        const int i8 = (t & 7) * 8;       // s-local
        #pragma unroll
        for (int p = 0; p < 2; ++p) {
            unsigned short tmp[8];
            #pragma unroll
            for (int e = 0; e < 8; ++e) tmp[e] = tile[i8 + e][p * 32 + j];
            *(uint4*)(outb + (size_t)(h0 + p * 32 + j) * S_ + s0 + i8) = *(uint4*)tmp;
        }
    }
}

// ---------------------------------------------------------------------------
// 256x256 GEMM, BK=32, triple-buffered (96 KiB), ONE barrier + ONE counted
// vmcnt(4) gate per K-tile (never 0 in-loop); tile kt+2 staged inside kt.
// NEW (r11): additive rotate swizzle on [256][32] tiles (both sides, rule 21):
//   LDS col16B c of row r holds G col (c - (r>>1)) mod 4.
//   Staging: gl2lds dest linear; lane fetches pre-rotated GLOBAL col
//     gcol16 = ((l&3) - ((l>>3)&3)) & 3      [rot = (row>>1)&3 = (l>>3)&3]
//   Reads: col16B = (lg + ((lm>>1)&3)) & 3   [row bases =0 mod 4 after >>1]
//   Slot check: slot8 = 4*(lm&1) + (lg+(lm>>1))&3 -> each 16-lane quarter
//   spreads over all 8 slots, 2 lanes/slot = free (m136). Was 8-way.
// WAR proof unchanged: buffer (kt+2)%3 last read in tile kt-1, finished by
// all waves before tile kt's boundary barrier.
// ---------------------------------------------------------------------------
template<int CF32>
__global__ __launch_bounds__(512, 2)
void gemm256_kernel(const unsigned short* __restrict__ A,
                    const unsigned short* __restrict__ Bt,
                    void* __restrict__ Cp, int Nst, int K)
{
    __shared__ alignas(16) unsigned short lds[3][2][256][32];  // 96 KiB

    const int t = threadIdx.x, l = t & 63, w = t >> 6;
    const int gx  = gridDim.x;
    const int nwg = gx * gridDim.y;
    int lin = blockIdx.y * gx + blockIdx.x;
    lin = (lin & 7) * (nwg >> 3) + (lin >> 3);       // bijective XCD swizzle (nwg%8==0)
    const int bn = (lin % gx) * 256, bm = (lin / gx) * 256;
    const int wr = w >> 2, wc = w & 3;               // 2 (M) x 4 (N) waves
    const int lm = l & 15, lg = l >> 4;

    f32x4 acc[8][4];
    #pragma unroll
    for (int i = 0; i < 8; ++i)
        #pragma unroll
        for (int j = 0; j < 4; ++j) acc[i][j] = (f32x4){0.f, 0.f, 0.f, 0.f};

    // staging: wave w covers rows {w*16..+15} and {128+w*16..}; pre-rotated source col
    const int srow = w * 16 + (l >> 2);
    const int scol = (((l & 3) - ((l >> 3) & 3)) & 3) * 8;   // swizzled global col (elems)
    const unsigned short* Asrc = A  + (size_t)(bm + srow) * K + scol;
    const unsigned short* Bsrc = Bt + (size_t)(bn + srow) * K + scol;

    // swizzled read col (lane-constant, elems)
    const int rcol = ((lg + ((lm >> 1) & 3)) & 3) * 8;

    #define STAGE_A(tt, bb) do {                                                  \
        gl2lds16(Asrc + (size_t)(tt) * 32,                  &lds[bb][0][w*16][0]); \
        gl2lds16(Asrc + (size_t)128*K + (size_t)(tt) * 32,  &lds[bb][0][128 + w*16][0]); } while (0)
    #define STAGE_B(tt, bb) do {                                                  \
        gl2lds16(Bsrc + (size_t)(tt) * 32,                  &lds[bb][1][w*16][0]); \
        gl2lds16(Bsrc + (size_t)128*K + (size_t)(tt) * 32,  &lds[bb][1][128 + w*16][0]); } while (0)

    const int nkt = K >> 5;
    STAGE_A(0, 0); STAGE_B(0, 0);
    STAGE_A(1, 1); STAGE_B(1, 1);

    for (int kt = 0; kt < nkt; ++kt) {
        if (kt + 1 < nkt) asm volatile("s_waitcnt vmcnt(4)" ::: "memory");
        else              asm volatile("s_waitcnt vmcnt(0)" ::: "memory");
        asm volatile("s_barrier" ::: "memory");

        const unsigned short (*bufA)[32] = lds[kt % 3][0];
        const unsigned short (*bufB)[32] = lds[kt % 3][1];
        const int nb = (kt + 2) % 3;
        const bool pf = (kt + 2 < nkt);

        bf16x8 bfr[4], afr[4];
        #pragma unroll
        for (int j = 0; j < 4; ++j) bfr[j] = *(const bf16x8*)&bufB[wc * 64 + j * 16 + lm][rcol];
        #pragma unroll
        for (int i = 0; i < 4; ++i) afr[i] = *(const bf16x8*)&bufA[wr * 128 + i * 16 + lm][rcol];
        if (pf) STAGE_A(kt + 2, nb);
        #pragma unroll
        for (int i = 0; i < 4; ++i)
            #pragma unroll
            for (int j = 0; j < 4; ++j)
                acc[i][j] = __builtin_amdgcn_mfma_f32_16x16x32_bf16(afr[i], bfr[j], acc[i][j], 0, 0, 0);

        #pragma unroll
        for (int i = 0; i < 4; ++i) afr[i] = *(const bf16x8*)&bufA[wr * 128 + (i + 4) * 16 + lm][rcol];
        if (pf) STAGE_B(kt + 2, nb);
        #pragma unroll
        for (int i = 0; i < 4; ++i)
            #pragma unroll
            for (int j = 0; j < 4; ++j)
                acc[i + 4][j] = __builtin_amdgcn_mfma_f32_16x16x32_bf16(afr[i], bfr[j], acc[i + 4][j], 0, 0, 0);
    }
    #undef STAGE_A
    #undef STAGE_B

    const int lr4 = lg * 4;
    #pragma unroll
    for (int i = 0; i < 8; ++i) {
        #pragma unroll
        for (int j = 0; j < 4; ++j) {
            int row = bm + wr * 128 + i * 16 + lr4;
            int col = bn + wc * 64 + j * 16 + lm;
            #pragma unroll
            for (int jj = 0; jj < 4; ++jj) {
                if constexpr (CF32)
                    ((float*)Cp)[(size_t)(row + jj) * Nst + col] = acc[i][j][jj];
                else
                    ((unsigned short*)Cp)[(size_t)(row + jj) * Nst + col] = f2bf(acc[i][j][jj]);
            }
        }
    }
}

// ---------------------------------------------------------------------------
// RoPE in-place on a slab of qkv (row stride NQKV).
// ---------------------------------------------------------------------------
template<int LOG2H>
__global__ __launch_bounds__(256)
void rope_kernel(unsigned short* __restrict__ data, const int* __restrict__ positions)
{
    const int gid  = blockIdx.x * 256 + threadIdx.x;
    const int j    = gid & 63;
    const int hr   = gid >> 6;
    const int head = hr & ((1 << LOG2H) - 1);
    const int bs   = hr >> LOG2H;
    const float pos = (float)positions[bs];
    const float inv = expf(-0.14391156831f * (float)j);
    float s, c;
    sincosf(pos * inv, &s, &c);
    const size_t base = (size_t)bs * NQKV + head * HD_;
    const float x1 = bf2f(data[base + j]);
    const float x2 = bf2f(data[base + 64 + j]);
    data[base + j]      = f2bf(x1 * c - x2 * s);
    data[base + 64 + j] = f2bf(x2 * c + x1 * s);
}

// ---------------------------------------------------------------------------
// MFMA flash attention, swapped-QK^T in-register softmax, gl2lds-staged K/V
// with rotate swizzle + double buffer (round-10, passing).
// ---------------------------------------------------------------------------
__global__ __launch_bounds__(256)
void attn_kernel(const unsigned short* __restrict__ qkv,
                 const unsigned short* __restrict__ vt,
                 unsigned short* __restrict__ ao)
{
    __shared__ alignas(16) unsigned short k_s[2][64][128];   // 32 KiB
    __shared__ alignas(16) unsigned short v_t[2][128][64];   // 32 KiB
    __shared__ alignas(16) unsigned short p_s[4][16][72];    // 9 KiB

    const int t   = threadIdx.x;
    const int blk = blockIdx.x;
    const int sb  = 31 - (blk >> 6);     // heavy (sb=31) blocks launch first
    const int pr  = blk & 63;
    const int qh  = pr >> 1;
    const int b   = pr & 1;
    const int kh  = qh >> 2;
    const int l   = t & 63, w = t >> 6;
    const int lm  = l & 15;
    const int lg  = l >> 4;
    const int lg4 = lg * 4;
    const int lko = lg * 8;
    const int wrow = w * 16 + lm;
    const int rot  = (lm & 7) * 8;       // read-side rotation (elems)

    const unsigned short* vtb = vt + (size_t)(b * NH_ + kh) * HD_ * S_;
    const size_t kvrow0 = (size_t)(b * S_) * NQKV + KOFF + kh * HD_;

    int ck[4], cv[2];
    #pragma unroll
    for (int kk = 0; kk < 4; ++kk) ck[kk] = (kk * 32 + lko - rot) & 127;
    #pragma unroll
    for (int kk = 0; kk < 2; ++kk) cv[kk] = (kk * 32 + lko - rot) & 63;

    const int krsub = l >> 4, ksseg = (l & 15) * 8;
    const int vrsub = l >> 3, vsseg = (l & 7) * 8;
    #define STAGEKV(cc, bb) do {                                                   \
        const int c64_ = (cc) * 64;                                                \
        _Pragma("unroll")                                                          \
        for (int i_ = 0; i_ < 4; ++i_) {                                           \
            const int kr_ = w * 16 + i_ * 4 + krsub;                               \
            const int ko_ = (ksseg + ((kr_ & 7) << 3)) & 127;                      \
            gl2lds16(qkv + kvrow0 + (size_t)(c64_ + kr_) * NQKV + ko_,             \
                     &k_s[bb][w * 16 + i_ * 4][0]);                                \
        }                                                                          \
        _Pragma("unroll")                                                          \
        for (int i_ = 0; i_ < 4; ++i_) {                                           \
            const int hv_ = w * 32 + i_ * 8 + vrsub;                               \
            const int vo_ = (vsseg + ((hv_ & 7) << 3)) & 63;                       \
            gl2lds16(vtb + (size_t)hv_ * S_ + c64_ + vo_,                          \
                     &v_t[bb][w * 32 + i_ * 8][0]);                                \
        }                                                                          \
    } while (0)

    bf16x8 qf[4];
    {
        const size_t qrow = (size_t)(b * S_ + sb * 64 + wrow) * NQKV + qh * HD_;
        #pragma unroll
        for (int kk = 0; kk < 4; ++kk)
            qf[kk] = *(const bf16x8*)(qkv + qrow + kk * 32 + lko);
    }

    f32x4 acc_o[8];
    #pragma unroll
    for (int i = 0; i < 8; ++i) acc_o[i] = (f32x4){0.f, 0.f, 0.f, 0.f};
    float mreg = -1e30f, lreg = 0.f;

    const float sm_scale = 0.08838834764831845f;

    STAGEKV(0, 0);

    for (int c = 0; c <= sb; ++c) {
        const int cur = c & 1;
        __syncthreads();
        if (c < sb) STAGEKV(c + 1, cur ^ 1);

        f32x4 acc_s[4];
        #pragma unroll
        for (int t4 = 0; t4 < 4; ++t4) acc_s[t4] = (f32x4){0.f, 0.f, 0.f, 0.f};
        #pragma unroll
        for (int kk = 0; kk < 4; ++kk) {
            const bf16x8 qv = qf[kk];
            bf16x8 kf0 = *(const bf16x8*)&k_s[cur][0 * 16 + lm][ck[kk]];
            bf16x8 kf1 = *(const bf16x8*)&k_s[cur][1 * 16 + lm][ck[kk]];
            bf16x8 kf2 = *(const bf16x8*)&k_s[cur][2 * 16 + lm][ck[kk]];
            bf16x8 kf3 = *(const bf16x8*)&k_s[cur][3 * 16 + lm][ck[kk]];
            __builtin_amdgcn_s_setprio(1);
            acc_s[0] = __builtin_amdgcn_mfma_f32_16x16x32_bf16(kf0, qv, acc_s[0], 0, 0, 0);
            acc_s[1] = __builtin_amdgcn_mfma_f32_16x16x32_bf16(kf1, qv, acc_s[1], 0, 0, 0);
            acc_s[2] = __builtin_amdgcn_mfma_f32_16x16x32_bf16(kf2, qv, acc_s[2], 0, 0, 0);
            acc_s[3] = __builtin_amdgcn_mfma_f32_16x16x32_bf16(kf3, qv, acc_s[3], 0, 0, 0);
            __builtin_amdgcn_s_setprio(0);
        }

        const bool diag = (c == sb);
        float p[4][4];
        #pragma unroll
        for (int t4 = 0; t4 < 4; ++t4)
            #pragma unroll
            for (int r = 0; r < 4; ++r) {
                float s = acc_s[t4][r] * sm_scale;
                if (diag && (t4 * 16 + lg4 + r > wrow)) s = -1e30f;
                p[t4][r] = s;
            }
        float mc = p[0][0];
        #pragma unroll
        for (int t4 = 0; t4 < 4; ++t4)
            #pragma unroll
            for (int r = 0; r < 4; ++r) mc = fmaxf(mc, p[t4][r]);
        mc = fmaxf(mc, __shfl_xor(mc, 16, 64));
        mc = fmaxf(mc, __shfl_xor(mc, 32, 64));
        float sf = 1.0f;
        if (mc > mreg + 8.0f) {
            sf = __expf(mreg - mc);
            mreg = mc;
            lreg *= sf;
        }
        if (__any(sf != 1.0f)) {
            #pragma unroll
            for (int r = 0; r < 4; ++r) {
                const float s_r = __shfl(sf, (l & 48) | (lg4 + r), 64);
                #pragma unroll
                for (int ht = 0; ht < 8; ++ht) acc_o[ht][r] *= s_r;
            }
        }
        float ps = 0.f;
        #pragma unroll
        for (int t4 = 0; t4 < 4; ++t4)
            #pragma unroll
            for (int r = 0; r < 4; ++r) {
                p[t4][r] = __expf(p[t4][r] - mreg);
                ps += p[t4][r];
            }
        ps += __shfl_xor(ps, 16, 64);
        ps += __shfl_xor(ps, 32, 64);
        lreg += ps;
        #pragma unroll
        for (int t4 = 0; t4 < 4; ++t4) {
            unsigned int d0 = (unsigned int)f2bf(p[t4][0]) | ((unsigned int)f2bf(p[t4][1]) << 16);
            unsigned int d1 = (unsigned int)f2bf(p[t4][2]) | ((unsigned int)f2bf(p[t4][3]) << 16);
            *(unsigned int*)&p_s[w][lm][t4 * 16 + lg4]     = d0;
            *(unsigned int*)&p_s[w][lm][t4 * 16 + lg4 + 2] = d1;
        }

        #pragma unroll
        for (int kk = 0; kk < 2; ++kk) {
            const bf16x8 pa = *(const bf16x8*)&p_s[w][lm][kk * 32 + lko];
            #pragma unroll
            for (int ht = 0; ht < 8; ht += 4) {
                bf16x8 bv0 = *(const bf16x8*)&v_t[cur][(ht + 0) * 16 + lm][cv[kk]];
                bf16x8 bv1 = *(const bf16x8*)&v_t[cur][(ht + 1) * 16 + lm][cv[kk]];
                bf16x8 bv2 = *(const bf16x8*)&v_t[cur][(ht + 2) * 16 + lm][cv[kk]];
                bf16x8 bv3 = *(const bf16x8*)&v_t[cur][(ht + 3) * 16 + lm][cv[kk]];
                __builtin_amdgcn_s_setprio(1);
                acc_o[ht + 0] = __builtin_amdgcn_mfma_f32_16x16x32_bf16(pa, bv0, acc_o[ht + 0], 0, 0, 0);
                acc_o[ht + 1] = __builtin_amdgcn_mfma_f32_16x16x32_bf16(pa, bv1, acc_o[ht + 1], 0, 0, 0);
                acc_o[ht + 2] = __builtin_amdgcn_mfma_f32_16x16x32_bf16(pa, bv2, acc_o[ht + 2], 0, 0, 0);
                acc_o[ht + 3] = __builtin_amdgcn_mfma_f32_16x16x32_bf16(pa, bv3, acc_o[ht + 3], 0, 0, 0);
                __builtin_amdgcn_s_setprio(0);
            }
        }
    }
    #undef STAGEKV

    #pragma unroll
    for (int r = 0; r < 4; ++r) {
        const float lr = __shfl(lreg, (l & 48) | (lg4 + r), 64);
        const float invl = 1.f / lr;
        const size_t row = (size_t)(b * S_ + sb * 64 + w * 16 + lg4 + r);
        #pragma unroll
        for (int ht = 0; ht < 8; ++ht)
            ao[(row * QH_ + qh) * HD_ + ht * 16 + lm] = f2bf(acc_o[ht][r] * invl);
    }
}

// ---------------------------------------------------------------------------
extern "C" void kernel_launch(void* const* d_in, const int* in_sizes, int n_in,
                              void* d_out, int out_size, void* d_ws, size_t ws_size,
                              hipStream_t stream)
{
    const float* x  = (const float*)d_in[0];
    const int*  pos = (const int*)d_in[1];
    const float* Wq = (const float*)d_in[2];
    const float* Wk = (const float*)d_in[3];
    const float* Wv = (const float*)d_in[4];
    const float* Wo = (const float*)d_in[5];
    float* out = (float*)d_out;

    char* wsb = (char*)d_ws;
    unsigned short* qkv = (unsigned short*)(wsb);              // 48 MiB [4096][6144]
    unsigned short* wt  = (unsigned short*)(wsb + 50331648);   // Wt_qkv 48M -> Wt_o 32M
    unsigned short* vt  = (unsigned short*)(wsb + 83886080);   // V^T
    unsigned short* r0  = (unsigned short*)(wsb + 100663296);  // 32 MiB x_bf -> ao

    const dim3 blk(256);
    const dim3 blk512(512);
    convert_bf16_kernel<<<8192, blk, 0, stream>>>(x, r0);
    transpose_conv_kernel<<<dim3(2, 64, 32), blk, 0, stream>>>(Wq, wt, D_, HD_);
    transpose_conv_kernel<<<dim3(2, 64, 8),  blk, 0, stream>>>(Wk, wt + (size_t)KOFF * D_, D_, HD_);
    transpose_conv_kernel<<<dim3(2, 64, 8),  blk, 0, stream>>>(Wv, wt + (size_t)VOFF * D_, D_, HD_);
    gemm256_kernel<0><<<dim3(NQKV / 256, MROWS / 256), blk512, 0, stream>>>(r0, wt, qkv, NQKV, D_);
    transpose_conv_kernel<<<dim3(64, 64, 1), blk, 0, stream>>>(Wo, wt, D_, D_);
    transpose_v_kernel<<<dim3(2, 32, 16), blk, 0, stream>>>(qkv, vt);
    rope_kernel<5><<<(MROWS * QH_ * 64) / 256, blk, 0, stream>>>(qkv, pos);
    rope_kernel<3><<<(MROWS * NH_ * 64) / 256, blk, 0, stream>>>(qkv + KOFF, pos);
    attn_kernel<<<B_ * QH_ * (S_ / 64), blk, 0, stream>>>(qkv, vt, r0);
    gemm256_kernel<1><<<dim3(D_ / 256, MROWS / 256), blk512, 0, stream>>>(r0, wt, out, D_, QH_ * HD_);
}

// Round 12
// 555.200 us; speedup vs baseline: 1.2065x; 1.0339x over previous
//
#include <hip/hip_runtime.h>
#include <cstdint>
#include <cstddef>

#define B_  2
#define S_  2048
#define D_  4096
#define QH_ 32
#define NH_ 8
#define HD_ 128
#define MROWS (B_ * S_)                      // 4096
#define NQKV  (QH_ * HD_ + 2 * NH_ * HD_)    // 6144
#define KOFF  (QH_ * HD_)                    // 4096
#define VOFF  (QH_ * HD_ + NH_ * HD_)        // 5120

typedef __attribute__((ext_vector_type(8))) short bf16x8;
typedef __attribute__((ext_vector_type(4))) float f32x4;

__device__ __forceinline__ unsigned short f2bf(float f) {
    unsigned int u = __float_as_uint(f);
    return (unsigned short)((u + 0x7FFFu + ((u >> 16) & 1u)) >> 16);
}
__device__ __forceinline__ float bf2f(unsigned short h) { return __uint_as_float(((unsigned int)h) << 16); }

__device__ __forceinline__ void gl2lds16(const void* g, void* l) {
    __builtin_amdgcn_global_load_lds(
        (const __attribute__((address_space(1))) void*)g,
        (__attribute__((address_space(3))) void*)l, 16, 0, 0);
}

// ---------------------------------------------------------------------------
// fp32 -> bf16 straight convert (x). 8 elems/thread.
// ---------------------------------------------------------------------------
__global__ __launch_bounds__(256)
void convert_bf16_kernel(const float* __restrict__ in, unsigned short* __restrict__ out)
{
    const size_t i = ((size_t)blockIdx.x * 256 + threadIdx.x) * 8;
    float4 a = *(const float4*)(in + i);
    float4 b = *(const float4*)(in + i + 4);
    uint4 o;
    o.x = (unsigned int)f2bf(a.x) | ((unsigned int)f2bf(a.y) << 16);
    o.y = (unsigned int)f2bf(a.z) | ((unsigned int)f2bf(a.w) << 16);
    o.z = (unsigned int)f2bf(b.x) | ((unsigned int)f2bf(b.y) << 16);
    o.w = (unsigned int)f2bf(b.z) | ((unsigned int)f2bf(b.w) << 16);
    *(uint4*)(out + i) = o;
}

// ---------------------------------------------------------------------------
// Tile transpose-convert: in fp32 [R][C] (slab z) -> out bf16 [C][R]
// ---------------------------------------------------------------------------
__global__ __launch_bounds__(256)
void transpose_conv_kernel(const float* __restrict__ in, unsigned short* __restrict__ out,
                           int R, int C)
{
    __shared__ unsigned short tile[64][72];
    const int t  = threadIdx.x;
    const int c0 = blockIdx.x * 64;
    const int r0 = blockIdx.y * 64;
    in  += (size_t)blockIdx.z * R * C;
    out += (size_t)blockIdx.z * R * C;
    {
        const int rr = t >> 4;
        const int cc = (t & 15) * 4;
        #pragma unroll
        for (int p = 0; p < 4; ++p) {
            float4 v = *(const float4*)(in + (size_t)(r0 + p * 16 + rr) * C + c0 + cc);
            unsigned int lo = (unsigned int)f2bf(v.x) | ((unsigned int)f2bf(v.y) << 16);
            unsigned int hi = (unsigned int)f2bf(v.z) | ((unsigned int)f2bf(v.w) << 16);
            *(uint2*)&tile[p * 16 + rr][cc] = make_uint2(lo, hi);
        }
    }
    __syncthreads();
    {
        const int j  = t >> 3;
        const int i8 = (t & 7) * 8;
        #pragma unroll
        for (int p = 0; p < 2; ++p) {
            unsigned short tmp[8];
            #pragma unroll
            for (int e = 0; e < 8; ++e) tmp[e] = tile[i8 + e][p * 32 + j];
            *(uint4*)(out + (size_t)(c0 + p * 32 + j) * R + r0 + i8) = *(uint4*)tmp;
        }
    }
}

// ---------------------------------------------------------------------------
// bf16 transpose of the V slab of qkv: -> vt[(b*8+kh)*128 + h][2048 s]
// ---------------------------------------------------------------------------
__global__ __launch_bounds__(256)
void transpose_v_kernel(const unsigned short* __restrict__ qkv, unsigned short* __restrict__ vt)
{
    __shared__ unsigned short tile[64][76];
    const int t  = threadIdx.x;
    const int z  = blockIdx.z;            // b*8+kh
    const int b  = z >> 3, kh = z & 7;
    const int h0 = blockIdx.x * 64;
    const int s0 = blockIdx.y * 64;
    const unsigned short* in = qkv + (size_t)(b * S_) * NQKV + VOFF + kh * HD_;
    unsigned short* outb = vt + (size_t)z * HD_ * S_;
    {
        const int rr = t >> 4;            // s-local
        const int cc = (t & 15) * 4;      // h-local
        #pragma unroll
        for (int p = 0; p < 4; ++p) {
            uint2 v = *(const uint2*)(in + (size_t)(s0 + p * 16 + rr) * NQKV + h0 + cc);
            *(uint2*)&tile[p * 16 + rr][cc] = v;
        }
    }
    __syncthreads();
    {
        const int j  = t >> 3;            // h-local 0..31
        const int i8 = (t & 7) * 8;       // s-local
        #pragma unroll
        for (int p = 0; p < 2; ++p) {
            unsigned short tmp[8];
            #pragma unroll
            for (int e = 0; e < 8; ++e) tmp[e] = tile[i8 + e][p * 32 + j];
            *(uint4*)(outb + (size_t)(h0 + p * 32 + j) * S_ + s0 + i8) = *(uint4*)tmp;
        }
    }
}

// ---------------------------------------------------------------------------
// 256x256 GEMM, BK=32, triple-buffered (96 KiB), ONE barrier + ONE counted
// vmcnt(4) gate per K-tile; tile kt+2 staged inside kt; rotate swizzle
// (round-11, conflicts == 0 verified).
// NEW (r12): N-frag remap: wave frag j at col j*64 + wc*16 (was wc*64+j*16).
// Bank math unchanged (row&1==lm&1; j*64, wc*16 == 0 mod 8 after >>1).
// Lane now owns both RoPE halves (col, col+64) as frags (j, j+1), j even ->
// ROPE template flag applies rotation in the epilogue for cols < VOFF:
//   fi = wc*16+lm (j-independent), inv = 10000^(-fi/64),
//   angle = positions[row] * inv, one sincosf per output row.
// ---------------------------------------------------------------------------
template<int CF32, int ROPE>
__global__ __launch_bounds__(512, 2)
void gemm256_kernel(const unsigned short* __restrict__ A,
                    const unsigned short* __restrict__ Bt,
                    void* __restrict__ Cp, const int* __restrict__ positions,
                    int Nst, int K)
{
    __shared__ alignas(16) unsigned short lds[3][2][256][32];  // 96 KiB

    const int t = threadIdx.x, l = t & 63, w = t >> 6;
    const int gx  = gridDim.x;
    const int nwg = gx * gridDim.y;
    int lin = blockIdx.y * gx + blockIdx.x;
    lin = (lin & 7) * (nwg >> 3) + (lin >> 3);       // bijective XCD swizzle (nwg%8==0)
    const int bn = (lin % gx) * 256, bm = (lin / gx) * 256;
    const int wr = w >> 2, wc = w & 3;               // 2 (M) x 4 (N) waves
    const int lm = l & 15, lg = l >> 4;

    f32x4 acc[8][4];
    #pragma unroll
    for (int i = 0; i < 8; ++i)
        #pragma unroll
        for (int j = 0; j < 4; ++j) acc[i][j] = (f32x4){0.f, 0.f, 0.f, 0.f};

    // staging: wave w covers rows {w*16..+15} and {128+w*16..}; pre-rotated source col
    const int srow = w * 16 + (l >> 2);
    const int scol = (((l & 3) - ((l >> 3) & 3)) & 3) * 8;   // swizzled global col (elems)
    const unsigned short* Asrc = A  + (size_t)(bm + srow) * K + scol;
    const unsigned short* Bsrc = Bt + (size_t)(bn + srow) * K + scol;

    // swizzled read col (lane-constant, elems)
    const int rcol = ((lg + ((lm >> 1) & 3)) & 3) * 8;

    #define STAGE_A(tt, bb) do {                                                  \
        gl2lds16(Asrc + (size_t)(tt) * 32,                  &lds[bb][0][w*16][0]); \
        gl2lds16(Asrc + (size_t)128*K + (size_t)(tt) * 32,  &lds[bb][0][128 + w*16][0]); } while (0)
    #define STAGE_B(tt, bb) do {                                                  \
        gl2lds16(Bsrc + (size_t)(tt) * 32,                  &lds[bb][1][w*16][0]); \
        gl2lds16(Bsrc + (size_t)128*K + (size_t)(tt) * 32,  &lds[bb][1][128 + w*16][0]); } while (0)

    const int nkt = K >> 5;
    STAGE_A(0, 0); STAGE_B(0, 0);
    STAGE_A(1, 1); STAGE_B(1, 1);

    for (int kt = 0; kt < nkt; ++kt) {
        if (kt + 1 < nkt) asm volatile("s_waitcnt vmcnt(4)" ::: "memory");
        else              asm volatile("s_waitcnt vmcnt(0)" ::: "memory");
        asm volatile("s_barrier" ::: "memory");

        const unsigned short (*bufA)[32] = lds[kt % 3][0];
        const unsigned short (*bufB)[32] = lds[kt % 3][1];
        const int nb = (kt + 2) % 3;
        const bool pf = (kt + 2 < nkt);

        bf16x8 bfr[4], afr[4];
        #pragma unroll
        for (int j = 0; j < 4; ++j) bfr[j] = *(const bf16x8*)&bufB[j * 64 + wc * 16 + lm][rcol];
        #pragma unroll
        for (int i = 0; i < 4; ++i) afr[i] = *(const bf16x8*)&bufA[wr * 128 + i * 16 + lm][rcol];
        if (pf) STAGE_A(kt + 2, nb);
        #pragma unroll
        for (int i = 0; i < 4; ++i)
            #pragma unroll
            for (int j = 0; j < 4; ++j)
                acc[i][j] = __builtin_amdgcn_mfma_f32_16x16x32_bf16(afr[i], bfr[j], acc[i][j], 0, 0, 0);

        #pragma unroll
        for (int i = 0; i < 4; ++i) afr[i] = *(const bf16x8*)&bufA[wr * 128 + (i + 4) * 16 + lm][rcol];
        if (pf) STAGE_B(kt + 2, nb);
        #pragma unroll
        for (int i = 0; i < 4; ++i)
            #pragma unroll
            for (int j = 0; j < 4; ++j)
                acc[i + 4][j] = __builtin_amdgcn_mfma_f32_16x16x32_bf16(afr[i], bfr[j], acc[i + 4][j], 0, 0, 0);
    }
    #undef STAGE_A
    #undef STAGE_B

    // C/D: col = lane&15 within frag, row = (lane>>4)*4 + reg.
    // Frag j -> col bn + j*64 + wc*16 + lm. RoPE: pairs (j, j+1), j even.
    const int lr4 = lg * 4;
    float invf = 0.f;
    if constexpr (ROPE) {
        const int fi = wc * 16 + lm;                 // 0..63, j-independent
        invf = expf(-0.14391156831f * (float)fi);    // 10000^(-fi/64)
    }
    #pragma unroll
    for (int i = 0; i < 8; ++i) {
        #pragma unroll
        for (int jj = 0; jj < 4; ++jj) {
            const int row = bm + wr * 128 + i * 16 + lr4 + jj;
            float sn = 0.f, cs = 1.f;
            if constexpr (ROPE) {
                const float pos = (float)positions[row];
                sincosf(pos * invf, &sn, &cs);
            }
            #pragma unroll
            for (int j = 0; j < 4; j += 2) {
                float x1 = acc[i][j][jj];
                float x2 = acc[i][j + 1][jj];
                const int col = bn + j * 64 + wc * 16 + lm;
                if constexpr (ROPE) {
                    if (col < VOFF) {                // Q/K heads only; V untouched
                        const float o1 = x1 * cs - x2 * sn;
                        const float o2 = x2 * cs + x1 * sn;
                        x1 = o1; x2 = o2;
                    }
                }
                if constexpr (CF32) {
                    ((float*)Cp)[(size_t)row * Nst + col]      = x1;
                    ((float*)Cp)[(size_t)row * Nst + col + 64] = x2;
                } else {
                    ((unsigned short*)Cp)[(size_t)row * Nst + col]      = f2bf(x1);
                    ((unsigned short*)Cp)[(size_t)row * Nst + col + 64] = f2bf(x2);
                }
            }
        }
    }
}

// ---------------------------------------------------------------------------
// MFMA flash attention, swapped-QK^T in-register softmax, gl2lds-staged K/V
// with rotate swizzle + double buffer (round-10/11, passing).
// ---------------------------------------------------------------------------
__global__ __launch_bounds__(256)
void attn_kernel(const unsigned short* __restrict__ qkv,
                 const unsigned short* __restrict__ vt,
                 unsigned short* __restrict__ ao)
{
    __shared__ alignas(16) unsigned short k_s[2][64][128];   // 32 KiB
    __shared__ alignas(16) unsigned short v_t[2][128][64];   // 32 KiB
    __shared__ alignas(16) unsigned short p_s[4][16][72];    // 9 KiB

    const int t   = threadIdx.x;
    const int blk = blockIdx.x;
    const int sb  = 31 - (blk >> 6);     // heavy (sb=31) blocks launch first
    const int pr  = blk & 63;
    const int qh  = pr >> 1;
    const int b   = pr & 1;
    const int kh  = qh >> 2;
    const int l   = t & 63, w = t >> 6;
    const int lm  = l & 15;
    const int lg  = l >> 4;
    const int lg4 = lg * 4;
    const int lko = lg * 8;
    const int wrow = w * 16 + lm;
    const int rot  = (lm & 7) * 8;       // read-side rotation (elems)

    const unsigned short* vtb = vt + (size_t)(b * NH_ + kh) * HD_ * S_;
    const size_t kvrow0 = (size_t)(b * S_) * NQKV + KOFF + kh * HD_;

    int ck[4], cv[2];
    #pragma unroll
    for (int kk = 0; kk < 4; ++kk) ck[kk] = (kk * 32 + lko - rot) & 127;
    #pragma unroll
    for (int kk = 0; kk < 2; ++kk) cv[kk] = (kk * 32 + lko - rot) & 63;

    const int krsub = l >> 4, ksseg = (l & 15) * 8;
    const int vrsub = l >> 3, vsseg = (l & 7) * 8;
    #define STAGEKV(cc, bb) do {                                                   \
        const int c64_ = (cc) * 64;                                                \
        _Pragma("unroll")                                                          \
        for (int i_ = 0; i_ < 4; ++i_) {                                           \
            const int kr_ = w * 16 + i_ * 4 + krsub;                               \
            const int ko_ = (ksseg + ((kr_ & 7) << 3)) & 127;                      \
            gl2lds16(qkv + kvrow0 + (size_t)(c64_ + kr_) * NQKV + ko_,             \
                     &k_s[bb][w * 16 + i_ * 4][0]);                                \
        }                                                                          \
        _Pragma("unroll")                                                          \
        for (int i_ = 0; i_ < 4; ++i_) {                                           \
            const int hv_ = w * 32 + i_ * 8 + vrsub;                               \
            const int vo_ = (vsseg + ((hv_ & 7) << 3)) & 63;                       \
            gl2lds16(vtb + (size_t)hv_ * S_ + c64_ + vo_,                          \
                     &v_t[bb][w * 32 + i_ * 8][0]);                                \
        }                                                                          \
    } while (0)

    bf16x8 qf[4];
    {
        const size_t qrow = (size_t)(b * S_ + sb * 64 + wrow) * NQKV + qh * HD_;
        #pragma unroll
        for (int kk = 0; kk < 4; ++kk)
            qf[kk] = *(const bf16x8*)(qkv + qrow + kk * 32 + lko);
    }

    f32x4 acc_o[8];
    #pragma unroll
    for (int i = 0; i < 8; ++i) acc_o[i] = (f32x4){0.f, 0.f, 0.f, 0.f};
    float mreg = -1e30f, lreg = 0.f;

    const float sm_scale = 0.08838834764831845f;

    STAGEKV(0, 0);

    for (int c = 0; c <= sb; ++c) {
        const int cur = c & 1;
        __syncthreads();
        if (c < sb) STAGEKV(c + 1, cur ^ 1);

        f32x4 acc_s[4];
        #pragma unroll
        for (int t4 = 0; t4 < 4; ++t4) acc_s[t4] = (f32x4){0.f, 0.f, 0.f, 0.f};
        #pragma unroll
        for (int kk = 0; kk < 4; ++kk) {
            const bf16x8 qv = qf[kk];
            bf16x8 kf0 = *(const bf16x8*)&k_s[cur][0 * 16 + lm][ck[kk]];
            bf16x8 kf1 = *(const bf16x8*)&k_s[cur][1 * 16 + lm][ck[kk]];
            bf16x8 kf2 = *(const bf16x8*)&k_s[cur][2 * 16 + lm][ck[kk]];
            bf16x8 kf3 = *(const bf16x8*)&k_s[cur][3 * 16 + lm][ck[kk]];
            __builtin_amdgcn_s_setprio(1);
            acc_s[0] = __builtin_amdgcn_mfma_f32_16x16x32_bf16(kf0, qv, acc_s[0], 0, 0, 0);
            acc_s[1] = __builtin_amdgcn_mfma_f32_16x16x32_bf16(kf1, qv, acc_s[1], 0, 0, 0);
            acc_s[2] = __builtin_amdgcn_mfma_f32_16x16x32_bf16(kf2, qv, acc_s[2], 0, 0, 0);
            acc_s[3] = __builtin_amdgcn_mfma_f32_16x16x32_bf16(kf3, qv, acc_s[3], 0, 0, 0);
            __builtin_amdgcn_s_setprio(0);
        }

        const bool diag = (c == sb);
        float p[4][4];
        #pragma unroll
        for (int t4 = 0; t4 < 4; ++t4)
            #pragma unroll
            for (int r = 0; r < 4; ++r) {
                float s = acc_s[t4][r] * sm_scale;
                if (diag && (t4 * 16 + lg4 + r > wrow)) s = -1e30f;
                p[t4][r] = s;
            }
        float mc = p[0][0];
        #pragma unroll
        for (int t4 = 0; t4 < 4; ++t4)
            #pragma unroll
            for (int r = 0; r < 4; ++r) mc = fmaxf(mc, p[t4][r]);
        mc = fmaxf(mc, __shfl_xor(mc, 16, 64));
        mc = fmaxf(mc, __shfl_xor(mc, 32, 64));
        float sf = 1.0f;
        if (mc > mreg + 8.0f) {
            sf = __expf(mreg - mc);
            mreg = mc;
            lreg *= sf;
        }
        if (__any(sf != 1.0f)) {
            #pragma unroll
            for (int r = 0; r < 4; ++r) {
                const float s_r = __shfl(sf, (l & 48) | (lg4 + r), 64);
                #pragma unroll
                for (int ht = 0; ht < 8; ++ht) acc_o[ht][r] *= s_r;
            }
        }
        float ps = 0.f;
        #pragma unroll
        for (int t4 = 0; t4 < 4; ++t4)
            #pragma unroll
            for (int r = 0; r < 4; ++r) {
                p[t4][r] = __expf(p[t4][r] - mreg);
                ps += p[t4][r];
            }
        ps += __shfl_xor(ps, 16, 64);
        ps += __shfl_xor(ps, 32, 64);
        lreg += ps;
        #pragma unroll
        for (int t4 = 0; t4 < 4; ++t4) {
            unsigned int d0 = (unsigned int)f2bf(p[t4][0]) | ((unsigned int)f2bf(p[t4][1]) << 16);
            unsigned int d1 = (unsigned int)f2bf(p[t4][2]) | ((unsigned int)f2bf(p[t4][3]) << 16);
            *(unsigned int*)&p_s[w][lm][t4 * 16 + lg4]     = d0;
            *(unsigned int*)&p_s[w][lm][t4 * 16 + lg4 + 2] = d1;
        }

        #pragma unroll
        for (int kk = 0; kk < 2; ++kk) {
            const bf16x8 pa = *(const bf16x8*)&p_s[w][lm][kk * 32 + lko];
            #pragma unroll
            for (int ht = 0; ht < 8; ht += 4) {
                bf16x8 bv0 = *(const bf16x8*)&v_t[cur][(ht + 0) * 16 + lm][cv[kk]];
                bf16x8 bv1 = *(const bf16x8*)&v_t[cur][(ht + 1) * 16 + lm][cv[kk]];
                bf16x8 bv2 = *(const bf16x8*)&v_t[cur][(ht + 2) * 16 + lm][cv[kk]];
                bf16x8 bv3 = *(const bf16x8*)&v_t[cur][(ht + 3) * 16 + lm][cv[kk]];
                __builtin_amdgcn_s_setprio(1);
                acc_o[ht + 0] = __builtin_amdgcn_mfma_f32_16x16x32_bf16(pa, bv0, acc_o[ht + 0], 0, 0, 0);
                acc_o[ht + 1] = __builtin_amdgcn_mfma_f32_16x16x32_bf16(pa, bv1, acc_o[ht + 1], 0, 0, 0);
                acc_o[ht + 2] = __builtin_amdgcn_mfma_f32_16x16x32_bf16(pa, bv2, acc_o[ht + 2], 0, 0, 0);
                acc_o[ht + 3] = __builtin_amdgcn_mfma_f32_16x16x32_bf16(pa, bv3, acc_o[ht + 3], 0, 0, 0);
                __builtin_amdgcn_s_setprio(0);
            }
        }
    }
    #undef STAGEKV

    #pragma unroll
    for (int r = 0; r < 4; ++r) {
        const float lr = __shfl(lreg, (l & 48) | (lg4 + r), 64);
        const float invl = 1.f / lr;
        const size_t row = (size_t)(b * S_ + sb * 64 + w * 16 + lg4 + r);
        #pragma unroll
        for (int ht = 0; ht < 8; ++ht)
            ao[(row * QH_ + qh) * HD_ + ht * 16 + lm] = f2bf(acc_o[ht][r] * invl);
    }
}

// ---------------------------------------------------------------------------
extern "C" void kernel_launch(void* const* d_in, const int* in_sizes, int n_in,
                              void* d_out, int out_size, void* d_ws, size_t ws_size,
                              hipStream_t stream)
{
    const float* x  = (const float*)d_in[0];
    const int*  pos = (const int*)d_in[1];
    const float* Wq = (const float*)d_in[2];
    const float* Wk = (const float*)d_in[3];
    const float* Wv = (const float*)d_in[4];
    const float* Wo = (const float*)d_in[5];
    float* out = (float*)d_out;

    char* wsb = (char*)d_ws;
    unsigned short* qkv = (unsigned short*)(wsb);              // 48 MiB [4096][6144]
    unsigned short* wt  = (unsigned short*)(wsb + 50331648);   // Wt_qkv 48M -> Wt_o 32M
    unsigned short* vt  = (unsigned short*)(wsb + 83886080);   // V^T
    unsigned short* r0  = (unsigned short*)(wsb + 100663296);  // 32 MiB x_bf -> ao

    const dim3 blk(256);
    const dim3 blk512(512);
    convert_bf16_kernel<<<8192, blk, 0, stream>>>(x, r0);
    transpose_conv_kernel<<<dim3(2, 64, 32), blk, 0, stream>>>(Wq, wt, D_, HD_);
    transpose_conv_kernel<<<dim3(2, 64, 8),  blk, 0, stream>>>(Wk, wt + (size_t)KOFF * D_, D_, HD_);
    transpose_conv_kernel<<<dim3(2, 64, 8),  blk, 0, stream>>>(Wv, wt + (size_t)VOFF * D_, D_, HD_);
    // fused QKV projection + RoPE (applied to cols < VOFF in epilogue)
    gemm256_kernel<0, 1><<<dim3(NQKV / 256, MROWS / 256), blk512, 0, stream>>>(
        r0, wt, qkv, pos, NQKV, D_);
    transpose_conv_kernel<<<dim3(64, 64, 1), blk, 0, stream>>>(Wo, wt, D_, D_);
    transpose_v_kernel<<<dim3(2, 32, 16), blk, 0, stream>>>(qkv, vt);
    attn_kernel<<<B_ * QH_ * (S_ / 64), blk, 0, stream>>>(qkv, vt, r0);
    // output projection -> fp32 out
    gemm256_kernel<1, 0><<<dim3(D_ / 256, MROWS / 256), blk512, 0, stream>>>(
        r0, wt, out, pos, D_, QH_ * HD_);
}

// Round 13
// 545.234 us; speedup vs baseline: 1.2286x; 1.0183x over previous
//
#include <hip/hip_runtime.h>
#include <cstdint>
#include <cstddef>

#define B_  2
#define S_  2048
#define D_  4096
#define QH_ 32
#define NH_ 8
#define HD_ 128
#define MROWS (B_ * S_)                      // 4096
#define NQKV  (QH_ * HD_ + 2 * NH_ * HD_)    // 6144
#define KOFF  (QH_ * HD_)                    // 4096
#define VOFF  (QH_ * HD_ + NH_ * HD_)        // 5120

typedef __attribute__((ext_vector_type(8))) short bf16x8;
typedef __attribute__((ext_vector_type(4))) float f32x4;

__device__ __forceinline__ unsigned short f2bf(float f) {
    unsigned int u = __float_as_uint(f);
    return (unsigned short)((u + 0x7FFFu + ((u >> 16) & 1u)) >> 16);
}
__device__ __forceinline__ float bf2f(unsigned short h) { return __uint_as_float(((unsigned int)h) << 16); }

__device__ __forceinline__ void gl2lds16(const void* g, void* l) {
    __builtin_amdgcn_global_load_lds(
        (const __attribute__((address_space(1))) void*)g,
        (__attribute__((address_space(3))) void*)l, 16, 0, 0);
}

// ---------------------------------------------------------------------------
// fp32 -> bf16 straight convert (x). 8 elems/thread.
// ---------------------------------------------------------------------------
__global__ __launch_bounds__(256)
void convert_bf16_kernel(const float* __restrict__ in, unsigned short* __restrict__ out)
{
    const size_t i = ((size_t)blockIdx.x * 256 + threadIdx.x) * 8;
    float4 a = *(const float4*)(in + i);
    float4 b = *(const float4*)(in + i + 4);
    uint4 o;
    o.x = (unsigned int)f2bf(a.x) | ((unsigned int)f2bf(a.y) << 16);
    o.y = (unsigned int)f2bf(a.z) | ((unsigned int)f2bf(a.w) << 16);
    o.z = (unsigned int)f2bf(b.x) | ((unsigned int)f2bf(b.y) << 16);
    o.w = (unsigned int)f2bf(b.z) | ((unsigned int)f2bf(b.w) << 16);
    *(uint4*)(out + i) = o;
}

// ---------------------------------------------------------------------------
// Tile transpose-convert: in fp32 [R][C] (slab z) -> out bf16 [C][R]
// ---------------------------------------------------------------------------
__global__ __launch_bounds__(256)
void transpose_conv_kernel(const float* __restrict__ in, unsigned short* __restrict__ out,
                           int R, int C)
{
    __shared__ unsigned short tile[64][72];
    const int t  = threadIdx.x;
    const int c0 = blockIdx.x * 64;
    const int r0 = blockIdx.y * 64;
    in  += (size_t)blockIdx.z * R * C;
    out += (size_t)blockIdx.z * R * C;
    {
        const int rr = t >> 4;
        const int cc = (t & 15) * 4;
        #pragma unroll
        for (int p = 0; p < 4; ++p) {
            float4 v = *(const float4*)(in + (size_t)(r0 + p * 16 + rr) * C + c0 + cc);
            unsigned int lo = (unsigned int)f2bf(v.x) | ((unsigned int)f2bf(v.y) << 16);
            unsigned int hi = (unsigned int)f2bf(v.z) | ((unsigned int)f2bf(v.w) << 16);
            *(uint2*)&tile[p * 16 + rr][cc] = make_uint2(lo, hi);
        }
    }
    __syncthreads();
    {
        const int j  = t >> 3;
        const int i8 = (t & 7) * 8;
        #pragma unroll
        for (int p = 0; p < 2; ++p) {
            unsigned short tmp[8];
            #pragma unroll
            for (int e = 0; e < 8; ++e) tmp[e] = tile[i8 + e][p * 32 + j];
            *(uint4*)(out + (size_t)(c0 + p * 32 + j) * R + r0 + i8) = *(uint4*)tmp;
        }
    }
}

// ---------------------------------------------------------------------------
// bf16 transpose of the V slab of qkv: -> vt[(b*8+kh)*128 + h][2048 s]
// ---------------------------------------------------------------------------
__global__ __launch_bounds__(256)
void transpose_v_kernel(const unsigned short* __restrict__ qkv, unsigned short* __restrict__ vt)
{
    __shared__ unsigned short tile[64][76];
    const int t  = threadIdx.x;
    const int z  = blockIdx.z;            // b*8+kh
    const int b  = z >> 3, kh = z & 7;
    const int h0 = blockIdx.x * 64;
    const int s0 = blockIdx.y * 64;
    const unsigned short* in = qkv + (size_t)(b * S_) * NQKV + VOFF + kh * HD_;
    unsigned short* outb = vt + (size_t)z * HD_ * S_;
    {
        const int rr = t >> 4;            // s-local
        const int cc = (t & 15) * 4;      // h-local
        #pragma unroll
        for (int p = 0; p < 4; ++p) {
            uint2 v = *(const uint2*)(in + (size_t)(s0 + p * 16 + rr) * NQKV + h0 + cc);
            *(uint2*)&tile[p * 16 + rr][cc] = v;
        }
    }
    __syncthreads();
    {
        const int j  = t >> 3;            // h-local 0..31
        const int i8 = (t & 7) * 8;       // s-local
        #pragma unroll
        for (int p = 0; p < 2; ++p) {
            unsigned short tmp[8];
            #pragma unroll
            for (int e = 0; e < 8; ++e) tmp[e] = tile[i8 + e][p * 32 + j];
            *(uint4*)(outb + (size_t)(h0 + p * 32 + j) * S_ + s0 + i8) = *(uint4*)tmp;
        }
    }
}

// ---------------------------------------------------------------------------
// 256x256 GEMM, BK=32, triple-buffered (96 KiB), ONE barrier + ONE counted
// vmcnt(4) gate per K-tile; tile kt+2 staged inside kt; rotate swizzle
// (round-11, conflicts == 0 verified). N-frag remap (r12): wave frag j at
// col j*64 + wc*16; lane owns both RoPE halves (col, col+64).
// r13: RoPE trig via NATIVE __sinf/__cosf (v_sin/v_cos + fract reduction,
// ~4 ops each) instead of libm sincosf (Payne-Hanek large-arg path) — the
// r12 epilogue cost ~40us of serialized VALU; angle error <=2e-4 rad,
// negligible vs bf16 rounding.
// ---------------------------------------------------------------------------
template<int CF32, int ROPE>
__global__ __launch_bounds__(512, 2)
void gemm256_kernel(const unsigned short* __restrict__ A,
                    const unsigned short* __restrict__ Bt,
                    void* __restrict__ Cp, const int* __restrict__ positions,
                    int Nst, int K)
{
    __shared__ alignas(16) unsigned short lds[3][2][256][32];  // 96 KiB

    const int t = threadIdx.x, l = t & 63, w = t >> 6;
    const int gx  = gridDim.x;
    const int nwg = gx * gridDim.y;
    int lin = blockIdx.y * gx + blockIdx.x;
    lin = (lin & 7) * (nwg >> 3) + (lin >> 3);       // bijective XCD swizzle (nwg%8==0)
    const int bn = (lin % gx) * 256, bm = (lin / gx) * 256;
    const int wr = w >> 2, wc = w & 3;               // 2 (M) x 4 (N) waves
    const int lm = l & 15, lg = l >> 4;

    f32x4 acc[8][4];
    #pragma unroll
    for (int i = 0; i < 8; ++i)
        #pragma unroll
        for (int j = 0; j < 4; ++j) acc[i][j] = (f32x4){0.f, 0.f, 0.f, 0.f};

    // staging: wave w covers rows {w*16..+15} and {128+w*16..}; pre-rotated source col
    const int srow = w * 16 + (l >> 2);
    const int scol = (((l & 3) - ((l >> 3) & 3)) & 3) * 8;   // swizzled global col (elems)
    const unsigned short* Asrc = A  + (size_t)(bm + srow) * K + scol;
    const unsigned short* Bsrc = Bt + (size_t)(bn + srow) * K + scol;

    // swizzled read col (lane-constant, elems)
    const int rcol = ((lg + ((lm >> 1) & 3)) & 3) * 8;

    #define STAGE_A(tt, bb) do {                                                  \
        gl2lds16(Asrc + (size_t)(tt) * 32,                  &lds[bb][0][w*16][0]); \
        gl2lds16(Asrc + (size_t)128*K + (size_t)(tt) * 32,  &lds[bb][0][128 + w*16][0]); } while (0)
    #define STAGE_B(tt, bb) do {                                                  \
        gl2lds16(Bsrc + (size_t)(tt) * 32,                  &lds[bb][1][w*16][0]); \
        gl2lds16(Bsrc + (size_t)128*K + (size_t)(tt) * 32,  &lds[bb][1][128 + w*16][0]); } while (0)

    const int nkt = K >> 5;
    STAGE_A(0, 0); STAGE_B(0, 0);
    STAGE_A(1, 1); STAGE_B(1, 1);

    for (int kt = 0; kt < nkt; ++kt) {
        if (kt + 1 < nkt) asm volatile("s_waitcnt vmcnt(4)" ::: "memory");
        else              asm volatile("s_waitcnt vmcnt(0)" ::: "memory");
        asm volatile("s_barrier" ::: "memory");

        const unsigned short (*bufA)[32] = lds[kt % 3][0];
        const unsigned short (*bufB)[32] = lds[kt % 3][1];
        const int nb = (kt + 2) % 3;
        const bool pf = (kt + 2 < nkt);

        bf16x8 bfr[4], afr[4];
        #pragma unroll
        for (int j = 0; j < 4; ++j) bfr[j] = *(const bf16x8*)&bufB[j * 64 + wc * 16 + lm][rcol];
        #pragma unroll
        for (int i = 0; i < 4; ++i) afr[i] = *(const bf16x8*)&bufA[wr * 128 + i * 16 + lm][rcol];
        if (pf) STAGE_A(kt + 2, nb);
        #pragma unroll
        for (int i = 0; i < 4; ++i)
            #pragma unroll
            for (int j = 0; j < 4; ++j)
                acc[i][j] = __builtin_amdgcn_mfma_f32_16x16x32_bf16(afr[i], bfr[j], acc[i][j], 0, 0, 0);

        #pragma unroll
        for (int i = 0; i < 4; ++i) afr[i] = *(const bf16x8*)&bufA[wr * 128 + (i + 4) * 16 + lm][rcol];
        if (pf) STAGE_B(kt + 2, nb);
        #pragma unroll
        for (int i = 0; i < 4; ++i)
            #pragma unroll
            for (int j = 0; j < 4; ++j)
                acc[i + 4][j] = __builtin_amdgcn_mfma_f32_16x16x32_bf16(afr[i], bfr[j], acc[i + 4][j], 0, 0, 0);
    }
    #undef STAGE_A
    #undef STAGE_B

    // C/D: col = lane&15 within frag, row = (lane>>4)*4 + reg.
    // Frag j -> col bn + j*64 + wc*16 + lm. RoPE: pairs (j, j+1), j even.
    const int lr4 = lg * 4;
    float invf = 0.f;
    if constexpr (ROPE) {
        const int fi = wc * 16 + lm;                 // 0..63, j-independent
        invf = expf(-0.14391156831f * (float)fi);    // 10000^(-fi/64)
    }
    #pragma unroll
    for (int i = 0; i < 8; ++i) {
        #pragma unroll
        for (int jj = 0; jj < 4; ++jj) {
            const int row = bm + wr * 128 + i * 16 + lr4 + jj;
            float sn = 0.f, cs = 1.f;
            if constexpr (ROPE) {
                const float ang = (float)positions[row] * invf;
                sn = __sinf(ang);                    // native v_sin path
                cs = __cosf(ang);                    // native v_cos path
            }
            #pragma unroll
            for (int j = 0; j < 4; j += 2) {
                float x1 = acc[i][j][jj];
                float x2 = acc[i][j + 1][jj];
                const int col = bn + j * 64 + wc * 16 + lm;
                if constexpr (ROPE) {
                    if (col < VOFF) {                // Q/K heads only; V untouched
                        const float o1 = x1 * cs - x2 * sn;
                        const float o2 = x2 * cs + x1 * sn;
                        x1 = o1; x2 = o2;
                    }
                }
                if constexpr (CF32) {
                    ((float*)Cp)[(size_t)row * Nst + col]      = x1;
                    ((float*)Cp)[(size_t)row * Nst + col + 64] = x2;
                } else {
                    ((unsigned short*)Cp)[(size_t)row * Nst + col]      = f2bf(x1);
                    ((unsigned short*)Cp)[(size_t)row * Nst + col + 64] = f2bf(x2);
                }
            }
        }
    }
}

// ---------------------------------------------------------------------------
// MFMA flash attention, swapped-QK^T in-register softmax, gl2lds-staged K/V
// with rotate swizzle + double buffer (round-10/11, passing).
// ---------------------------------------------------------------------------
__global__ __launch_bounds__(256)
void attn_kernel(const unsigned short* __restrict__ qkv,
                 const unsigned short* __restrict__ vt,
                 unsigned short* __restrict__ ao)
{
    __shared__ alignas(16) unsigned short k_s[2][64][128];   // 32 KiB
    __shared__ alignas(16) unsigned short v_t[2][128][64];   // 32 KiB
    __shared__ alignas(16) unsigned short p_s[4][16][72];    // 9 KiB

    const int t   = threadIdx.x;
    const int blk = blockIdx.x;
    const int sb  = 31 - (blk >> 6);     // heavy (sb=31) blocks launch first
    const int pr  = blk & 63;
    const int qh  = pr >> 1;
    const int b   = pr & 1;
    const int kh  = qh >> 2;
    const int l   = t & 63, w = t >> 6;
    const int lm  = l & 15;
    const int lg  = l >> 4;
    const int lg4 = lg * 4;
    const int lko = lg * 8;
    const int wrow = w * 16 + lm;
    const int rot  = (lm & 7) * 8;       // read-side rotation (elems)

    const unsigned short* vtb = vt + (size_t)(b * NH_ + kh) * HD_ * S_;
    const size_t kvrow0 = (size_t)(b * S_) * NQKV + KOFF + kh * HD_;

    int ck[4], cv[2];
    #pragma unroll
    for (int kk = 0; kk < 4; ++kk) ck[kk] = (kk * 32 + lko - rot) & 127;
    #pragma unroll
    for (int kk = 0; kk < 2; ++kk) cv[kk] = (kk * 32 + lko - rot) & 63;

    const int krsub = l >> 4, ksseg = (l & 15) * 8;
    const int vrsub = l >> 3, vsseg = (l & 7) * 8;
    #define STAGEKV(cc, bb) do {                                                   \
        const int c64_ = (cc) * 64;                                                \
        _Pragma("unroll")                                                          \
        for (int i_ = 0; i_ < 4; ++i_) {                                           \
            const int kr_ = w * 16 + i_ * 4 + krsub;                               \
            const int ko_ = (ksseg + ((kr_ & 7) << 3)) & 127;                      \
            gl2lds16(qkv + kvrow0 + (size_t)(c64_ + kr_) * NQKV + ko_,             \
                     &k_s[bb][w * 16 + i_ * 4][0]);                                \
        }                                                                          \
        _Pragma("unroll")                                                          \
        for (int i_ = 0; i_ < 4; ++i_) {                                           \
            const int hv_ = w * 32 + i_ * 8 + vrsub;                               \
            const int vo_ = (vsseg + ((hv_ & 7) << 3)) & 63;                       \
            gl2lds16(vtb + (size_t)hv_ * S_ + c64_ + vo_,                          \
                     &v_t[bb][w * 32 + i_ * 8][0]);                                \
        }                                                                          \
    } while (0)

    bf16x8 qf[4];
    {
        const size_t qrow = (size_t)(b * S_ + sb * 64 + wrow) * NQKV + qh * HD_;
        #pragma unroll
        for (int kk = 0; kk < 4; ++kk)
            qf[kk] = *(const bf16x8*)(qkv + qrow + kk * 32 + lko);
    }

    f32x4 acc_o[8];
    #pragma unroll
    for (int i = 0; i < 8; ++i) acc_o[i] = (f32x4){0.f, 0.f, 0.f, 0.f};
    float mreg = -1e30f, lreg = 0.f;

    const float sm_scale = 0.08838834764831845f;

    STAGEKV(0, 0);

    for (int c = 0; c <= sb; ++c) {
        const int cur = c & 1;
        __syncthreads();
        if (c < sb) STAGEKV(c + 1, cur ^ 1);

        f32x4 acc_s[4];
        #pragma unroll
        for (int t4 = 0; t4 < 4; ++t4) acc_s[t4] = (f32x4){0.f, 0.f, 0.f, 0.f};
        #pragma unroll
        for (int kk = 0; kk < 4; ++kk) {
            const bf16x8 qv = qf[kk];
            bf16x8 kf0 = *(const bf16x8*)&k_s[cur][0 * 16 + lm][ck[kk]];
            bf16x8 kf1 = *(const bf16x8*)&k_s[cur][1 * 16 + lm][ck[kk]];
            bf16x8 kf2 = *(const bf16x8*)&k_s[cur][2 * 16 + lm][ck[kk]];
            bf16x8 kf3 = *(const bf16x8*)&k_s[cur][3 * 16 + lm][ck[kk]];
            __builtin_amdgcn_s_setprio(1);
            acc_s[0] = __builtin_amdgcn_mfma_f32_16x16x32_bf16(kf0, qv, acc_s[0], 0, 0, 0);
            acc_s[1] = __builtin_amdgcn_mfma_f32_16x16x32_bf16(kf1, qv, acc_s[1], 0, 0, 0);
            acc_s[2] = __builtin_amdgcn_mfma_f32_16x16x32_bf16(kf2, qv, acc_s[2], 0, 0, 0);
            acc_s[3] = __builtin_amdgcn_mfma_f32_16x16x32_bf16(kf3, qv, acc_s[3], 0, 0, 0);
            __builtin_amdgcn_s_setprio(0);
        }

        const bool diag = (c == sb);
        float p[4][4];
        #pragma unroll
        for (int t4 = 0; t4 < 4; ++t4)
            #pragma unroll
            for (int r = 0; r < 4; ++r) {
                float s = acc_s[t4][r] * sm_scale;
                if (diag && (t4 * 16 + lg4 + r > wrow)) s = -1e30f;
                p[t4][r] = s;
            }
        float mc = p[0][0];
        #pragma unroll
        for (int t4 = 0; t4 < 4; ++t4)
            #pragma unroll
            for (int r = 0; r < 4; ++r) mc = fmaxf(mc, p[t4][r]);
        mc = fmaxf(mc, __shfl_xor(mc, 16, 64));
        mc = fmaxf(mc, __shfl_xor(mc, 32, 64));
        float sf = 1.0f;
        if (mc > mreg + 8.0f) {
            sf = __expf(mreg - mc);
            mreg = mc;
            lreg *= sf;
        }
        if (__any(sf != 1.0f)) {
            #pragma unroll
            for (int r = 0; r < 4; ++r) {
                const float s_r = __shfl(sf, (l & 48) | (lg4 + r), 64);
                #pragma unroll
                for (int ht = 0; ht < 8; ++ht) acc_o[ht][r] *= s_r;
            }
        }
        float ps = 0.f;
        #pragma unroll
        for (int t4 = 0; t4 < 4; ++t4)
            #pragma unroll
            for (int r = 0; r < 4; ++r) {
                p[t4][r] = __expf(p[t4][r] - mreg);
                ps += p[t4][r];
            }
        ps += __shfl_xor(ps, 16, 64);
        ps += __shfl_xor(ps, 32, 64);
        lreg += ps;
        #pragma unroll
        for (int t4 = 0; t4 < 4; ++t4) {
            unsigned int d0 = (unsigned int)f2bf(p[t4][0]) | ((unsigned int)f2bf(p[t4][1]) << 16);
            unsigned int d1 = (unsigned int)f2bf(p[t4][2]) | ((unsigned int)f2bf(p[t4][3]) << 16);
            *(unsigned int*)&p_s[w][lm][t4 * 16 + lg4]     = d0;
            *(unsigned int*)&p_s[w][lm][t4 * 16 + lg4 + 2] = d1;
        }

        #pragma unroll
        for (int kk = 0; kk < 2; ++kk) {
            const bf16x8 pa = *(const bf16x8*)&p_s[w][lm][kk * 32 + lko];
            #pragma unroll
            for (int ht = 0; ht < 8; ht += 4) {
                bf16x8 bv0 = *(const bf16x8*)&v_t[cur][(ht + 0) * 16 + lm][cv[kk]];
                bf16x8 bv1 = *(const bf16x8*)&v_t[cur][(ht + 1) * 16 + lm][cv[kk]];
                bf16x8 bv2 = *(const bf16x8*)&v_t[cur][(ht + 2) * 16 + lm][cv[kk]];
                bf16x8 bv3 = *(const bf16x8*)&v_t[cur][(ht + 3) * 16 + lm][cv[kk]];
                __builtin_amdgcn_s_setprio(1);
                acc_o[ht + 0] = __builtin_amdgcn_mfma_f32_16x16x32_bf16(pa, bv0, acc_o[ht + 0], 0, 0, 0);
                acc_o[ht + 1] = __builtin_amdgcn_mfma_f32_16x16x32_bf16(pa, bv1, acc_o[ht + 1], 0, 0, 0);
                acc_o[ht + 2] = __builtin_amdgcn_mfma_f32_16x16x32_bf16(pa, bv2, acc_o[ht + 2], 0, 0, 0);
                acc_o[ht + 3] = __builtin_amdgcn_mfma_f32_16x16x32_bf16(pa, bv3, acc_o[ht + 3], 0, 0, 0);
                __builtin_amdgcn_s_setprio(0);
            }
        }
    }
    #undef STAGEKV

    #pragma unroll
    for (int r = 0; r < 4; ++r) {
        const float lr = __shfl(lreg, (l & 48) | (lg4 + r), 64);
        const float invl = 1.f / lr;
        const size_t row = (size_t)(b * S_ + sb * 64 + w * 16 + lg4 + r);
        #pragma unroll
        for (int ht = 0; ht < 8; ++ht)
            ao[(row * QH_ + qh) * HD_ + ht * 16 + lm] = f2bf(acc_o[ht][r] * invl);
    }
}

// ---------------------------------------------------------------------------
extern "C" void kernel_launch(void* const* d_in, const int* in_sizes, int n_in,
                              void* d_out, int out_size, void* d_ws, size_t ws_size,
                              hipStream_t stream)
{
    const float* x  = (const float*)d_in[0];
    const int*  pos = (const int*)d_in[1];
    const float* Wq = (const float*)d_in[2];
    const float* Wk = (const float*)d_in[3];
    const float* Wv = (const float*)d_in[4];
    const float* Wo = (const float*)d_in[5];
    float* out = (float*)d_out;

    char* wsb = (char*)d_ws;
    unsigned short* qkv = (unsigned short*)(wsb);              // 48 MiB [4096][6144]
    unsigned short* wt  = (unsigned short*)(wsb + 50331648);   // Wt_qkv 48M -> Wt_o 32M
    unsigned short* vt  = (unsigned short*)(wsb + 83886080);   // V^T
    unsigned short* r0  = (unsigned short*)(wsb + 100663296);  // 32 MiB x_bf -> ao

    const dim3 blk(256);
    const dim3 blk512(512);
    convert_bf16_kernel<<<8192, blk, 0, stream>>>(x, r0);
    transpose_conv_kernel<<<dim3(2, 64, 32), blk, 0, stream>>>(Wq, wt, D_, HD_);
    transpose_conv_kernel<<<dim3(2, 64, 8),  blk, 0, stream>>>(Wk, wt + (size_t)KOFF * D_, D_, HD_);
    transpose_conv_kernel<<<dim3(2, 64, 8),  blk, 0, stream>>>(Wv, wt + (size_t)VOFF * D_, D_, HD_);
    // fused QKV projection + RoPE (applied to cols < VOFF in epilogue)
    gemm256_kernel<0, 1><<<dim3(NQKV / 256, MROWS / 256), blk512, 0, stream>>>(
        r0, wt, qkv, pos, NQKV, D_);
    transpose_conv_kernel<<<dim3(64, 64, 1), blk, 0, stream>>>(Wo, wt, D_, D_);
    transpose_v_kernel<<<dim3(2, 32, 16), blk, 0, stream>>>(qkv, vt);
    attn_kernel<<<B_ * QH_ * (S_ / 64), blk, 0, stream>>>(qkv, vt, r0);
    // output projection -> fp32 out
    gemm256_kernel<1, 0><<<dim3(D_ / 256, MROWS / 256), blk512, 0, stream>>>(
        r0, wt, out, pos, D_, QH_ * HD_);
}